// Round 1
// baseline (330.513 us; speedup 1.0000x reference)
//
#include <hip/hip_runtime.h>
#include <hip/hip_bf16.h>

// GCN 2-layer: N=50000 nodes, E=800000 edges, 128->128(relu)->64.
// Strategy: build dst-CSR (counting sort) once per call, then pull-aggregate.

#define NODES_PER_BLOCK 4

__global__ void init_cnt_k(int* cnt, int n) {
  int i = blockIdx.x * blockDim.x + threadIdx.x;
  if (i < n) cnt[i] = 0;
}

// edge_index may arrive as int32 or as int64 (little-endian word pairs).
// Values < 50000 => int64 high words are all zero; random int32 edge values
// are essentially never 64-in-a-row zero at odd positions.
__global__ void detect64_k(const int* ei, int* flag) {
  if (blockIdx.x == 0 && threadIdx.x == 0) {
    int z = 1;
    for (int i = 0; i < 64; ++i)
      if (ei[2 * i + 1] != 0) { z = 0; break; }
    *flag = z;
  }
}

__global__ void count_k(const int* __restrict__ ei, const int* __restrict__ flag,
                        int* cnt, int E) {
  int e = blockIdx.x * blockDim.x + threadIdx.x;
  if (e >= E) return;
  int is64 = *flag;
  int d = is64 ? ei[2 * ((size_t)E + e)] : ei[(size_t)E + e];
  atomicAdd(&cnt[d], 1);
}

__global__ void dinv_k(const int* __restrict__ cnt, float* dinv, int n) {
  int i = blockIdx.x * blockDim.x + threadIdx.x;
  if (i < n) dinv[i] = rsqrtf((float)(cnt[i] + 1));  // +1 self-loop
}

// ---- 3-kernel exclusive scan of cnt[0..n) -> offsets[0..n], cursor copy ----
#define SCAN_CHUNK 4096

__global__ __launch_bounds__(256) void scan1_k(const int* __restrict__ cnt,
                                               int* partials, int n) {
  __shared__ int sd[256];
  int t = threadIdx.x;
  int base = blockIdx.x * SCAN_CHUNK;
  int s = 0;
  for (int i = t; i < SCAN_CHUNK; i += 256) {
    int idx = base + i;
    s += (idx < n) ? cnt[idx] : 0;
  }
  sd[t] = s;
  __syncthreads();
  for (int off = 128; off > 0; off >>= 1) {
    if (t < off) sd[t] += sd[t + off];
    __syncthreads();
  }
  if (t == 0) partials[blockIdx.x] = sd[0];
}

__global__ void scan2_k(const int* partials, int* bases, int nb,
                        int* offsets, int n, int E) {
  if (blockIdx.x == 0 && threadIdx.x == 0) {
    int run = 0;
    for (int b = 0; b < nb; ++b) { bases[b] = run; run += partials[b]; }
    offsets[n] = E;
  }
}

__global__ __launch_bounds__(256) void scan3_k(const int* __restrict__ cnt,
                                               const int* __restrict__ bases,
                                               int* offsets, int* cursor, int n) {
  __shared__ int ts[256];
  int t = threadIdx.x;
  int base = blockIdx.x * SCAN_CHUNK + t * 16;
  int v[16];
  int s = 0;
#pragma unroll
  for (int i = 0; i < 16; ++i) {
    int idx = base + i;
    int c = (idx < n) ? cnt[idx] : 0;
    v[i] = s;  // exclusive within thread
    s += c;
  }
  int incl = s;
  ts[t] = incl;
  __syncthreads();
  for (int off = 1; off < 256; off <<= 1) {
    int add = (t >= off) ? ts[t - off] : 0;
    __syncthreads();
    incl += add;
    ts[t] = incl;
    __syncthreads();
  }
  int tbase = bases[blockIdx.x] + (incl - s);
#pragma unroll
  for (int i = 0; i < 16; ++i) {
    int idx = base + i;
    if (idx < n) {
      int o = tbase + v[i];
      offsets[idx] = o;
      cursor[idx] = o;
    }
  }
}

__global__ void fill_k(const int* __restrict__ ei, const int* __restrict__ flag,
                       int* cursor, int* csr_src, int E) {
  int e = blockIdx.x * blockDim.x + threadIdx.x;
  if (e >= E) return;
  int is64 = *flag;
  int s, d;
  if (is64) {
    s = ei[2 * (size_t)e];
    d = ei[2 * ((size_t)E + e)];
  } else {
    s = ei[e];
    d = ei[(size_t)E + e];
  }
  int pos = atomicAdd(&cursor[d], 1);
  csr_src[pos] = s;
}

// ---- GEMM: H[M,NC] = X[M,128] @ W[128,NC], f32, NC in {128, 64} ----
template <int NC>
__global__ __launch_bounds__(256) void gemm_k128(const float* __restrict__ X,
                                                 const float* __restrict__ W,
                                                 float* __restrict__ H, int M) {
  constexpr int BK = 32;
  constexpr int CN = NC / 16;  // cols per thread (8 or 4)
  __shared__ float Xs[64][BK + 1];
  __shared__ float Ws[BK][NC];
  int tid = threadIdx.x;
  int tx = tid & 15;       // 0..15 col group
  int ty = tid >> 4;       // 0..15 row group
  int row0 = blockIdx.x * 64;

  float acc[4][CN];
#pragma unroll
  for (int i = 0; i < 4; ++i)
#pragma unroll
    for (int j = 0; j < CN; ++j) acc[i][j] = 0.0f;

  for (int k0 = 0; k0 < 128; k0 += BK) {
    // stage X tile: 64 x 32 floats = 512 float4, 2 per thread
#pragma unroll
    for (int l = tid; l < 512; l += 256) {
      int r = l >> 3;
      int kq = (l & 7) * 4;
      int gr = row0 + r;
      float4 val;
      if (gr < M)
        val = *(const float4*)(X + (size_t)gr * 128 + k0 + kq);
      else
        val = make_float4(0.f, 0.f, 0.f, 0.f);
      Xs[r][kq + 0] = val.x;
      Xs[r][kq + 1] = val.y;
      Xs[r][kq + 2] = val.z;
      Xs[r][kq + 3] = val.w;
    }
    // stage W tile: BK x NC floats
    constexpr int WTOT = BK * NC / 4;
#pragma unroll
    for (int l = tid; l < WTOT; l += 256) {
      int kk = l / (NC / 4);
      int cq = (l % (NC / 4)) * 4;
      *(float4*)&Ws[kk][cq] = *(const float4*)(W + (size_t)(k0 + kk) * NC + cq);
    }
    __syncthreads();

#pragma unroll
    for (int kk = 0; kk < BK; ++kk) {
      float xv[4];
#pragma unroll
      for (int i = 0; i < 4; ++i) xv[i] = Xs[ty * 4 + i][kk];
      float wv[CN];
#pragma unroll
      for (int j = 0; j < CN; j += 4) {
        float4 wq = *(const float4*)&Ws[kk][tx * CN + j];
        wv[j + 0] = wq.x; wv[j + 1] = wq.y; wv[j + 2] = wq.z; wv[j + 3] = wq.w;
      }
#pragma unroll
      for (int i = 0; i < 4; ++i)
#pragma unroll
        for (int j = 0; j < CN; ++j) acc[i][j] = fmaf(xv[i], wv[j], acc[i][j]);
    }
    __syncthreads();
  }

#pragma unroll
  for (int i = 0; i < 4; ++i) {
    int gr = row0 + ty * 4 + i;
    if (gr < M) {
#pragma unroll
      for (int j = 0; j < CN; j += 4) {
        *(float4*)&H[(size_t)gr * NC + tx * CN + j] =
            make_float4(acc[i][j], acc[i][j + 1], acc[i][j + 2], acc[i][j + 3]);
      }
    }
  }
}

// ---- Aggregation: out[i] = act( dinv[i]*(sum_e dinv[s]*h[s] + dinv[i]*h[i]) + b ) ----
__global__ __launch_bounds__(256) void agg1_k(const float* __restrict__ h,
                                              const float* __restrict__ dinv,
                                              const int* __restrict__ offsets,
                                              const int* __restrict__ csr_src,
                                              const float* __restrict__ b,
                                              float* __restrict__ y, int n) {
  int wave = threadIdx.x >> 6;
  int lane = threadIdx.x & 63;
  int node = blockIdx.x * NODES_PER_BLOCK + wave;
  if (node >= n) return;
  float di = dinv[node];
  const float2* hp = (const float2*)h;
  float2 acc = hp[(size_t)node * 64 + lane];
  acc.x *= di;
  acc.y *= di;
  int beg = offsets[node], end = offsets[node + 1];
  for (int e = beg; e < end; ++e) {
    int s = csr_src[e];
    float ds = dinv[s];
    float2 v = hp[(size_t)s * 64 + lane];
    acc.x = fmaf(ds, v.x, acc.x);
    acc.y = fmaf(ds, v.y, acc.y);
  }
  float2 bb = ((const float2*)b)[lane];
  float2 o;
  o.x = fmaxf(fmaf(di, acc.x, bb.x), 0.0f);
  o.y = fmaxf(fmaf(di, acc.y, bb.y), 0.0f);
  ((float2*)y)[(size_t)node * 64 + lane] = o;
}

__global__ __launch_bounds__(256) void agg2_k(const float* __restrict__ h,
                                              const float* __restrict__ dinv,
                                              const int* __restrict__ offsets,
                                              const int* __restrict__ csr_src,
                                              const float* __restrict__ b,
                                              float* __restrict__ out, int n) {
  int wave = threadIdx.x >> 6;
  int lane = threadIdx.x & 63;
  int node = blockIdx.x * NODES_PER_BLOCK + wave;
  if (node >= n) return;
  float di = dinv[node];
  float acc = h[(size_t)node * 64 + lane] * di;
  int beg = offsets[node], end = offsets[node + 1];
  for (int e = beg; e < end; ++e) {
    int s = csr_src[e];
    acc = fmaf(dinv[s], h[(size_t)s * 64 + lane], acc);
  }
  out[(size_t)node * 64 + lane] = fmaf(di, acc, b[lane]);
}

extern "C" void kernel_launch(void* const* d_in, const int* in_sizes, int n_in,
                              void* d_out, int out_size, void* d_ws, size_t ws_size,
                              hipStream_t stream) {
  const float* x  = (const float*)d_in[0];
  const int*   ei = (const int*)d_in[1];
  const float* W1 = (const float*)d_in[2];
  const float* b1 = (const float*)d_in[3];
  const float* W2 = (const float*)d_in[4];
  const float* b2 = (const float*)d_in[5];
  float* out = (float*)d_out;

  const int N = in_sizes[0] / 128;   // 50000
  const int E = in_sizes[1] / 2;     // 800000 (element count halved regardless of dtype)

  // workspace carve-up (512B-aligned)
  char* w = (char*)d_ws;
  size_t off = 0;
  auto alloc = [&](size_t bytes) -> void* {
    void* p = w + off;
    off = (off + bytes + 511) & ~(size_t)511;
    return p;
  };
  int*   cnt     = (int*)alloc((size_t)N * 4);
  float* dinv    = (float*)alloc((size_t)N * 4);
  int*   offsets = (int*)alloc((size_t)(N + 1) * 4);
  int*   cursor  = (int*)alloc((size_t)N * 4);
  int*   small   = (int*)alloc(512);           // partials @0, bases @64, flag @128
  int*   partials = small;
  int*   bases    = small + 64;
  int*   flag     = small + 128;
  int*   csr_src = (int*)alloc((size_t)E * 4);
  float* h       = (float*)alloc((size_t)N * 128 * 4);  // h1; reused as h2
  float* y       = (float*)alloc((size_t)N * 128 * 4);  // relu output

  const int NB_N = (N + 255) / 256;
  const int NB_E = (E + 255) / 256;
  const int SB   = (N + SCAN_CHUNK - 1) / SCAN_CHUNK;
  const int GB   = (N + 63) / 64;
  const int AB   = (N + NODES_PER_BLOCK - 1) / NODES_PER_BLOCK;

  init_cnt_k<<<NB_N, 256, 0, stream>>>(cnt, N);
  detect64_k<<<1, 64, 0, stream>>>(ei, flag);
  count_k<<<NB_E, 256, 0, stream>>>(ei, flag, cnt, E);
  dinv_k<<<NB_N, 256, 0, stream>>>(cnt, dinv, N);
  scan1_k<<<SB, 256, 0, stream>>>(cnt, partials, N);
  scan2_k<<<1, 1, 0, stream>>>(partials, bases, SB, offsets, N, E);
  scan3_k<<<SB, 256, 0, stream>>>(cnt, bases, offsets, cursor, N);
  fill_k<<<NB_E, 256, 0, stream>>>(ei, flag, cursor, csr_src, E);

  gemm_k128<128><<<GB, 256, 0, stream>>>(x, W1, h, N);
  agg1_k<<<AB, 256, 0, stream>>>(h, dinv, offsets, csr_src, b1, y, N);
  gemm_k128<64><<<GB, 256, 0, stream>>>(y, W2, h, N);
  agg2_k<<<AB, 256, 0, stream>>>(h, dinv, offsets, csr_src, b2, out, N);
}

// Round 3
// 259.315 us; speedup vs baseline: 1.2746x; 1.2746x over previous
//
#include <hip/hip_runtime.h>
#include <hip/hip_bf16.h>

// GCN 2-layer: N=50000 nodes, E=800000 edges, 128->128(relu)->64.
// dst-CSR build + f32 GEMM with fused dinv-prescale (f32 storage),
// pull-aggregation with shfl-broadcast src indices + 8-deep unrolled gathers.

#define NODES_PER_BLOCK 4

typedef unsigned int uint;

__global__ void init_cnt_k(int* cnt, int n) {
  int i = blockIdx.x * blockDim.x + threadIdx.x;
  if (i < n) cnt[i] = 0;
}

// edge_index may arrive as int32 or int64 (word pairs). Values < 50000 =>
// int64 high words all zero.
__global__ void detect64_k(const int* ei, int* flag) {
  if (blockIdx.x == 0 && threadIdx.x == 0) {
    int z = 1;
    for (int i = 0; i < 64; ++i)
      if (ei[2 * i + 1] != 0) { z = 0; break; }
    *flag = z;
  }
}

__global__ void count_k(const int* __restrict__ ei, const int* __restrict__ flag,
                        int* cnt, int E) {
  int e = blockIdx.x * blockDim.x + threadIdx.x;
  if (e >= E) return;
  int is64 = *flag;
  int d = is64 ? ei[2 * ((size_t)E + e)] : ei[(size_t)E + e];
  atomicAdd(&cnt[d], 1);
}

__global__ void dinv_k(const int* __restrict__ cnt, float* dinv, int n) {
  int i = blockIdx.x * blockDim.x + threadIdx.x;
  if (i < n) dinv[i] = rsqrtf((float)(cnt[i] + 1));  // +1 self-loop
}

// ---- 3-kernel exclusive scan of cnt[0..n) -> offsets[0..n], cursor copy ----
#define SCAN_CHUNK 4096

__global__ __launch_bounds__(256) void scan1_k(const int* __restrict__ cnt,
                                               int* partials, int n) {
  __shared__ int sd[256];
  int t = threadIdx.x;
  int base = blockIdx.x * SCAN_CHUNK;
  int s = 0;
  for (int i = t; i < SCAN_CHUNK; i += 256) {
    int idx = base + i;
    s += (idx < n) ? cnt[idx] : 0;
  }
  sd[t] = s;
  __syncthreads();
  for (int off = 128; off > 0; off >>= 1) {
    if (t < off) sd[t] += sd[t + off];
    __syncthreads();
  }
  if (t == 0) partials[blockIdx.x] = sd[0];
}

__global__ void scan2_k(const int* partials, int* bases, int nb,
                        int* offsets, int n, int E) {
  if (blockIdx.x == 0 && threadIdx.x == 0) {
    int run = 0;
    for (int b = 0; b < nb; ++b) { bases[b] = run; run += partials[b]; }
    offsets[n] = E;
  }
}

__global__ __launch_bounds__(256) void scan3_k(const int* __restrict__ cnt,
                                               const int* __restrict__ bases,
                                               int* offsets, int* cursor, int n) {
  __shared__ int ts[256];
  int t = threadIdx.x;
  int base = blockIdx.x * SCAN_CHUNK + t * 16;
  int v[16];
  int s = 0;
#pragma unroll
  for (int i = 0; i < 16; ++i) {
    int idx = base + i;
    int c = (idx < n) ? cnt[idx] : 0;
    v[i] = s;
    s += c;
  }
  int incl = s;
  ts[t] = incl;
  __syncthreads();
  for (int off = 1; off < 256; off <<= 1) {
    int add = (t >= off) ? ts[t - off] : 0;
    __syncthreads();
    incl += add;
    ts[t] = incl;
    __syncthreads();
  }
  int tbase = bases[blockIdx.x] + (incl - s);
#pragma unroll
  for (int i = 0; i < 16; ++i) {
    int idx = base + i;
    if (idx < n) {
      int o = tbase + v[i];
      offsets[idx] = o;
      cursor[idx] = o;
    }
  }
}

__global__ void fill_k(const int* __restrict__ ei, const int* __restrict__ flag,
                       int* cursor, int* csr_src, int E) {
  int e = blockIdx.x * blockDim.x + threadIdx.x;
  if (e >= E) return;
  int is64 = *flag;
  int s, d;
  if (is64) {
    s = ei[2 * (size_t)e];
    d = ei[2 * ((size_t)E + e)];
  } else {
    s = ei[e];
    d = ei[(size_t)E + e];
  }
  int pos = atomicAdd(&cursor[d], 1);
  csr_src[pos] = s;
}

// ---- GEMM: H[M,NC](f32) = dinv[row] * (X[M,128] @ W[128,NC]) ----
template <int NC>
__global__ __launch_bounds__(256) void gemm_k128(const float* __restrict__ X,
                                                 const float* __restrict__ W,
                                                 const float* __restrict__ dinv,
                                                 float* __restrict__ H, int M) {
  constexpr int BK = 32;
  constexpr int CN = NC / 16;  // cols per thread (8 or 4)
  __shared__ float Xs[64][BK + 1];
  __shared__ float Ws[BK][NC];
  int tid = threadIdx.x;
  int tx = tid & 15;
  int ty = tid >> 4;
  int row0 = blockIdx.x * 64;

  float acc[4][CN];
#pragma unroll
  for (int i = 0; i < 4; ++i)
#pragma unroll
    for (int j = 0; j < CN; ++j) acc[i][j] = 0.0f;

  for (int k0 = 0; k0 < 128; k0 += BK) {
#pragma unroll
    for (int l = tid; l < 512; l += 256) {
      int r = l >> 3;
      int kq = (l & 7) * 4;
      int gr = row0 + r;
      float4 val;
      if (gr < M)
        val = *(const float4*)(X + (size_t)gr * 128 + k0 + kq);
      else
        val = make_float4(0.f, 0.f, 0.f, 0.f);
      Xs[r][kq + 0] = val.x;
      Xs[r][kq + 1] = val.y;
      Xs[r][kq + 2] = val.z;
      Xs[r][kq + 3] = val.w;
    }
    constexpr int WTOT = BK * NC / 4;
#pragma unroll
    for (int l = tid; l < WTOT; l += 256) {
      int kk = l / (NC / 4);
      int cq = (l % (NC / 4)) * 4;
      *(float4*)&Ws[kk][cq] = *(const float4*)(W + (size_t)(k0 + kk) * NC + cq);
    }
    __syncthreads();

#pragma unroll
    for (int kk = 0; kk < BK; ++kk) {
      float xv[4];
#pragma unroll
      for (int i = 0; i < 4; ++i) xv[i] = Xs[ty * 4 + i][kk];
      float wv[CN];
#pragma unroll
      for (int j = 0; j < CN; j += 4) {
        float4 wq = *(const float4*)&Ws[kk][tx * CN + j];
        wv[j + 0] = wq.x; wv[j + 1] = wq.y; wv[j + 2] = wq.z; wv[j + 3] = wq.w;
      }
#pragma unroll
      for (int i = 0; i < 4; ++i)
#pragma unroll
        for (int j = 0; j < CN; ++j) acc[i][j] = fmaf(xv[i], wv[j], acc[i][j]);
    }
    __syncthreads();
  }

#pragma unroll
  for (int i = 0; i < 4; ++i) {
    int gr = row0 + ty * 4 + i;
    if (gr < M) {
      float di = dinv[gr];
#pragma unroll
      for (int j = 0; j < CN; j += 4) {
        *(float4*)&H[(size_t)gr * NC + tx * CN + j] =
            make_float4(di * acc[i][j], di * acc[i][j + 1],
                        di * acc[i][j + 2], di * acc[i][j + 3]);
      }
    }
  }
}

// ---- agg1: y[i] = relu( dinv_i * (h'_i + sum_src h'_src) + b1 ), 128 feats ----
// h' rows are float2-per-lane (512B/row). Indices preloaded per-lane, shfl-
// broadcast; 8 independent gathers in flight.
__global__ __launch_bounds__(256) void agg1_k(const float2* __restrict__ hp,
                                              const float* __restrict__ dinv,
                                              const int* __restrict__ offsets,
                                              const int* __restrict__ csr_src,
                                              const float* __restrict__ b,
                                              float* __restrict__ y, int n) {
  int wave = threadIdx.x >> 6;
  int lane = threadIdx.x & 63;
  int node = blockIdx.x * NODES_PER_BLOCK + wave;
  if (node >= n) return;
  int beg = offsets[node], end = offsets[node + 1];
  int deg = end - beg;
  float2 self = hp[(size_t)node * 64 + lane];
  float ax = self.x, ay = self.y;
  int sv = 0;
  if (lane < deg) sv = csr_src[beg + lane];
  int lim = deg < 64 ? deg : 64;
  int e = 0;
  for (; e + 8 <= lim; e += 8) {
    int s0 = __shfl(sv, e + 0), s1 = __shfl(sv, e + 1);
    int s2 = __shfl(sv, e + 2), s3 = __shfl(sv, e + 3);
    int s4 = __shfl(sv, e + 4), s5 = __shfl(sv, e + 5);
    int s6 = __shfl(sv, e + 6), s7 = __shfl(sv, e + 7);
    float2 v0 = hp[(size_t)s0 * 64 + lane];
    float2 v1 = hp[(size_t)s1 * 64 + lane];
    float2 v2 = hp[(size_t)s2 * 64 + lane];
    float2 v3 = hp[(size_t)s3 * 64 + lane];
    float2 v4 = hp[(size_t)s4 * 64 + lane];
    float2 v5 = hp[(size_t)s5 * 64 + lane];
    float2 v6 = hp[(size_t)s6 * 64 + lane];
    float2 v7 = hp[(size_t)s7 * 64 + lane];
    ax += ((v0.x + v1.x) + (v2.x + v3.x)) + ((v4.x + v5.x) + (v6.x + v7.x));
    ay += ((v0.y + v1.y) + (v2.y + v3.y)) + ((v4.y + v5.y) + (v6.y + v7.y));
  }
  for (; e < lim; ++e) {
    int s = __shfl(sv, e);
    float2 v = hp[(size_t)s * 64 + lane];
    ax += v.x;
    ay += v.y;
  }
  for (int ee = beg + 64; ee < end; ++ee) {  // deg>64 fallback (essentially never)
    int s = csr_src[ee];
    float2 v = hp[(size_t)s * 64 + lane];
    ax += v.x;
    ay += v.y;
  }
  float di = dinv[node];
  float2 bb = ((const float2*)b)[lane];
  float2 o;
  o.x = fmaxf(fmaf(di, ax, bb.x), 0.0f);
  o.y = fmaxf(fmaf(di, ay, bb.y), 0.0f);
  ((float2*)y)[(size_t)node * 64 + lane] = o;
}

// ---- agg2: out[i] = dinv_i * (h'_i + sum_src h'_src) + b2, 64 feats ----
__global__ __launch_bounds__(256) void agg2_k(const float* __restrict__ hp,
                                              const float* __restrict__ dinv,
                                              const int* __restrict__ offsets,
                                              const int* __restrict__ csr_src,
                                              const float* __restrict__ b,
                                              float* __restrict__ out, int n) {
  int wave = threadIdx.x >> 6;
  int lane = threadIdx.x & 63;
  int node = blockIdx.x * NODES_PER_BLOCK + wave;
  if (node >= n) return;
  int beg = offsets[node], end = offsets[node + 1];
  int deg = end - beg;
  float acc = hp[(size_t)node * 64 + lane];
  int sv = 0;
  if (lane < deg) sv = csr_src[beg + lane];
  int lim = deg < 64 ? deg : 64;
  int e = 0;
  for (; e + 8 <= lim; e += 8) {
    int s0 = __shfl(sv, e + 0), s1 = __shfl(sv, e + 1);
    int s2 = __shfl(sv, e + 2), s3 = __shfl(sv, e + 3);
    int s4 = __shfl(sv, e + 4), s5 = __shfl(sv, e + 5);
    int s6 = __shfl(sv, e + 6), s7 = __shfl(sv, e + 7);
    float v0 = hp[(size_t)s0 * 64 + lane];
    float v1 = hp[(size_t)s1 * 64 + lane];
    float v2 = hp[(size_t)s2 * 64 + lane];
    float v3 = hp[(size_t)s3 * 64 + lane];
    float v4 = hp[(size_t)s4 * 64 + lane];
    float v5 = hp[(size_t)s5 * 64 + lane];
    float v6 = hp[(size_t)s6 * 64 + lane];
    float v7 = hp[(size_t)s7 * 64 + lane];
    acc += ((v0 + v1) + (v2 + v3)) + ((v4 + v5) + (v6 + v7));
  }
  for (; e < lim; ++e) {
    int s = __shfl(sv, e);
    acc += hp[(size_t)s * 64 + lane];
  }
  for (int ee = beg + 64; ee < end; ++ee) {  // deg>64 fallback
    acc += hp[(size_t)csr_src[ee] * 64 + lane];
  }
  float di = dinv[node];
  out[(size_t)node * 64 + lane] = fmaf(di, acc, b[lane]);
}

extern "C" void kernel_launch(void* const* d_in, const int* in_sizes, int n_in,
                              void* d_out, int out_size, void* d_ws, size_t ws_size,
                              hipStream_t stream) {
  const float* x  = (const float*)d_in[0];
  const int*   ei = (const int*)d_in[1];
  const float* W1 = (const float*)d_in[2];
  const float* b1 = (const float*)d_in[3];
  const float* W2 = (const float*)d_in[4];
  const float* b2 = (const float*)d_in[5];
  float* out = (float*)d_out;

  const int N = in_sizes[0] / 128;   // 50000
  const int E = in_sizes[1] / 2;     // 800000

  char* w = (char*)d_ws;
  size_t off = 0;
  auto alloc = [&](size_t bytes) -> void* {
    void* p = w + off;
    off = (off + bytes + 511) & ~(size_t)511;
    return p;
  };
  int*   cnt     = (int*)alloc((size_t)N * 4);
  float* dinv    = (float*)alloc((size_t)N * 4);
  int*   offsets = (int*)alloc((size_t)(N + 1) * 4);
  int*   cursor  = (int*)alloc((size_t)N * 4);
  int*   small   = (int*)alloc(512);           // partials @0, bases @64, flag @128
  int*   partials = small;
  int*   bases    = small + 64;
  int*   flag     = small + 128;
  int*   csr_src = (int*)alloc((size_t)E * 4);
  float* h1      = (float*)alloc((size_t)N * 128 * 4);  // dinv-scaled h1
  float* y       = (float*)alloc((size_t)N * 128 * 4);  // relu output
  float* h2      = (float*)alloc((size_t)N * 64 * 4);   // dinv-scaled h2

  const int NB_N = (N + 255) / 256;
  const int NB_E = (E + 255) / 256;
  const int SB   = (N + SCAN_CHUNK - 1) / SCAN_CHUNK;
  const int GB   = (N + 63) / 64;
  const int AB   = (N + NODES_PER_BLOCK - 1) / NODES_PER_BLOCK;

  init_cnt_k<<<NB_N, 256, 0, stream>>>(cnt, N);
  detect64_k<<<1, 64, 0, stream>>>(ei, flag);
  count_k<<<NB_E, 256, 0, stream>>>(ei, flag, cnt, E);
  dinv_k<<<NB_N, 256, 0, stream>>>(cnt, dinv, N);
  scan1_k<<<SB, 256, 0, stream>>>(cnt, partials, N);
  scan2_k<<<1, 1, 0, stream>>>(partials, bases, SB, offsets, N, E);
  scan3_k<<<SB, 256, 0, stream>>>(cnt, bases, offsets, cursor, N);
  fill_k<<<NB_E, 256, 0, stream>>>(ei, flag, cursor, csr_src, E);

  gemm_k128<128><<<GB, 256, 0, stream>>>(x, W1, dinv, h1, N);
  agg1_k<<<AB, 256, 0, stream>>>((const float2*)h1, dinv, offsets, csr_src, b1, y, N);
  gemm_k128<64><<<GB, 256, 0, stream>>>(y, W2, dinv, h2, N);
  agg2_k<<<AB, 256, 0, stream>>>(h2, dinv, offsets, csr_src, b2, out, N);
}

// Round 4
// 181.293 us; speedup vs baseline: 1.8231x; 1.4304x over previous
//
#include <hip/hip_runtime.h>
#include <hip/hip_bf16.h>

// GCN 2-layer: N=50000 nodes, E=800000 edges, 128->128(relu)->64.
// CSR build via two-level LDS-binned partition (no global atomics),
// f32 GEMM with fused dinv-prescale, pull-aggregation with shfl-broadcast
// indices + 8-deep unrolled gathers.

#define NODES_PER_BLOCK 4
#define CHUNK 4096   // edges per partition chunk
#define BCAP 8192    // max edges per 256-node bucket held in LDS

typedef unsigned int uint;

// edge_index may arrive as int32 or int64 (word pairs). Values < 50000 =>
// int64 high words all zero.
__global__ void detect64_k(const int* ei, int* flag) {
  if (blockIdx.x == 0 && threadIdx.x == 0) {
    int z = 1;
    for (int i = 0; i < 64; ++i)
      if (ei[2 * i + 1] != 0) { z = 0; break; }
    *flag = z;
  }
}

// A1: per-chunk histogram over coarse buckets (dst >> 8)
__global__ __launch_bounds__(256) void hist_k(const int* __restrict__ ei,
                                              const int* __restrict__ flag,
                                              int* __restrict__ gh,
                                              int E, int nchunk, int nbuck) {
  __shared__ int h[256];
  int c = blockIdx.x;
  for (int i = threadIdx.x; i < 256; i += 256) h[i] = 0;
  __syncthreads();
  int is64 = *flag;
  int base = c * CHUNK;
  int lim = min(CHUNK, E - base);
  for (int i = threadIdx.x; i < lim; i += 256) {
    int e = base + i;
    int d = is64 ? ei[2 * ((size_t)E + e)] : ei[(size_t)E + e];
    atomicAdd(&h[d >> 8], 1);
  }
  __syncthreads();
  for (int k = threadIdx.x; k < nbuck; k += 256) gh[k * nchunk + c] = h[k];
}

// A2a: per-bucket totals
__global__ __launch_bounds__(256) void tot_k(const int* __restrict__ gh,
                                             int* __restrict__ totals, int nchunk) {
  __shared__ int sd[256];
  int k = blockIdx.x;
  int s = 0;
  for (int i = threadIdx.x; i < nchunk; i += 256) s += gh[k * nchunk + i];
  sd[threadIdx.x] = s;
  __syncthreads();
  for (int o = 128; o > 0; o >>= 1) {
    if (threadIdx.x < o) sd[threadIdx.x] += sd[threadIdx.x + o];
    __syncthreads();
  }
  if (threadIdx.x == 0) totals[k] = sd[0];
}

// A2c: block k: bucketStart[k] + in-place scan of gh row -> absolute bases.
// Requires nbuck <= 256 and nchunk <= 256 (196/196 here).
__global__ __launch_bounds__(256) void scanrow_k(int* __restrict__ gh,
                                                 const int* __restrict__ totals,
                                                 int* __restrict__ bucketStart,
                                                 int* __restrict__ offsets,
                                                 int nchunk, int nbuck, int N, int E) {
  __shared__ int st[256];
  int k = blockIdx.x;
  int t = threadIdx.x;
  int v = (t < nbuck && t < k) ? totals[t] : 0;
  st[t] = v;
  __syncthreads();
  for (int o = 128; o > 0; o >>= 1) {
    if (t < o) st[t] += st[t + o];
    __syncthreads();
  }
  int bs = st[0];
  if (t == 0) {
    bucketStart[k] = bs;
    if (k == nbuck - 1) { bucketStart[nbuck] = E; offsets[N] = E; }
  }
  __syncthreads();
  int x = (t < nchunk) ? gh[k * nchunk + t] : 0;
  st[t] = x;
  __syncthreads();
  int incl = x;
  for (int o = 1; o < 256; o <<= 1) {
    int add = (t >= o) ? st[t - o] : 0;
    __syncthreads();
    incl += add;
    st[t] = incl;
    __syncthreads();
  }
  if (t < nchunk) gh[k * nchunk + t] = bs + (incl - x);
}

// A3: partition edges into bucket-grouped tmp, packed (src16 | dstlow8<<16)
__global__ __launch_bounds__(256) void part_k(const int* __restrict__ ei,
                                              const int* __restrict__ flag,
                                              const int* __restrict__ gh,
                                              int* __restrict__ tmp,
                                              int E, int nchunk, int nbuck) {
  __shared__ int cur[256];
  int c = blockIdx.x;
  for (int i = threadIdx.x; i < nbuck; i += 256) cur[i] = gh[i * nchunk + c];
  __syncthreads();
  int is64 = *flag;
  int base = c * CHUNK;
  int lim = min(CHUNK, E - base);
  for (int i = threadIdx.x; i < lim; i += 256) {
    int e = base + i;
    int s, d;
    if (is64) {
      s = ei[2 * (size_t)e];
      d = ei[2 * ((size_t)E + e)];
    } else {
      s = ei[e];
      d = ei[(size_t)E + e];
    }
    int p = atomicAdd(&cur[d >> 8], 1);
    tmp[p] = s | ((d & 255) << 16);
  }
}

// B: one block per bucket: LDS count+scan -> offsets, dinv, node-grouped csr_src
__global__ __launch_bounds__(256) void bucket_k(const int* __restrict__ tmp,
                                                const int* __restrict__ bucketStart,
                                                int* __restrict__ csr_src,
                                                int* __restrict__ offsets,
                                                float* __restrict__ dinv,
                                                int N) {
  __shared__ int ebuf[BCAP];
  __shared__ int cnt[256];
  __shared__ int st[256];
  __shared__ int lofs[256];
  int k = blockIdx.x;
  int b0 = bucketStart[k], b1 = bucketStart[k + 1];
  int sz = b1 - b0;
  int t = threadIdx.x;
  cnt[t] = 0;
  __syncthreads();
  bool inlds = (sz <= BCAP);
  if (inlds) {
    for (int i = t; i < sz; i += 256) {
      int v = tmp[b0 + i];
      ebuf[i] = v;
      atomicAdd(&cnt[v >> 16], 1);
    }
  } else {
    for (int i = t; i < sz; i += 256) atomicAdd(&cnt[tmp[b0 + i] >> 16], 1);
  }
  __syncthreads();
  int x = cnt[t];
  st[t] = x;
  __syncthreads();
  int incl = x;
  for (int o = 1; o < 256; o <<= 1) {
    int add = (t >= o) ? st[t - o] : 0;
    __syncthreads();
    incl += add;
    st[t] = incl;
    __syncthreads();
  }
  lofs[t] = incl - x;
  int node = k * 256 + t;
  if (node < N) {
    offsets[node] = b0 + lofs[t];
    dinv[node] = rsqrtf((float)(x + 1));  // +1 self-loop
  }
  __syncthreads();
  cnt[t] = lofs[t];  // reuse as cursor
  __syncthreads();
  if (inlds) {
    for (int i = t; i < sz; i += 256) {
      int v = ebuf[i];
      int p = atomicAdd(&cnt[v >> 16], 1);
      csr_src[b0 + p] = v & 0xFFFF;
    }
  } else {
    for (int i = t; i < sz; i += 256) {
      int v = tmp[b0 + i];
      int p = atomicAdd(&cnt[v >> 16], 1);
      csr_src[b0 + p] = v & 0xFFFF;
    }
  }
}

// ---- GEMM: H[M,NC](f32) = dinv[row] * (X[M,128] @ W[128,NC]) ----
template <int NC>
__global__ __launch_bounds__(256) void gemm_k128(const float* __restrict__ X,
                                                 const float* __restrict__ W,
                                                 const float* __restrict__ dinv,
                                                 float* __restrict__ H, int M) {
  constexpr int BK = 32;
  constexpr int CN = NC / 16;
  __shared__ float Xs[64][BK + 1];
  __shared__ float Ws[BK][NC];
  int tid = threadIdx.x;
  int tx = tid & 15;
  int ty = tid >> 4;
  int row0 = blockIdx.x * 64;

  float acc[4][CN];
#pragma unroll
  for (int i = 0; i < 4; ++i)
#pragma unroll
    for (int j = 0; j < CN; ++j) acc[i][j] = 0.0f;

  for (int k0 = 0; k0 < 128; k0 += BK) {
#pragma unroll
    for (int l = tid; l < 512; l += 256) {
      int r = l >> 3;
      int kq = (l & 7) * 4;
      int gr = row0 + r;
      float4 val;
      if (gr < M)
        val = *(const float4*)(X + (size_t)gr * 128 + k0 + kq);
      else
        val = make_float4(0.f, 0.f, 0.f, 0.f);
      Xs[r][kq + 0] = val.x;
      Xs[r][kq + 1] = val.y;
      Xs[r][kq + 2] = val.z;
      Xs[r][kq + 3] = val.w;
    }
    constexpr int WTOT = BK * NC / 4;
#pragma unroll
    for (int l = tid; l < WTOT; l += 256) {
      int kk = l / (NC / 4);
      int cq = (l % (NC / 4)) * 4;
      *(float4*)&Ws[kk][cq] = *(const float4*)(W + (size_t)(k0 + kk) * NC + cq);
    }
    __syncthreads();

#pragma unroll
    for (int kk = 0; kk < BK; ++kk) {
      float xv[4];
#pragma unroll
      for (int i = 0; i < 4; ++i) xv[i] = Xs[ty * 4 + i][kk];
      float wv[CN];
#pragma unroll
      for (int j = 0; j < CN; j += 4) {
        float4 wq = *(const float4*)&Ws[kk][tx * CN + j];
        wv[j + 0] = wq.x; wv[j + 1] = wq.y; wv[j + 2] = wq.z; wv[j + 3] = wq.w;
      }
#pragma unroll
      for (int i = 0; i < 4; ++i)
#pragma unroll
        for (int j = 0; j < CN; ++j) acc[i][j] = fmaf(xv[i], wv[j], acc[i][j]);
    }
    __syncthreads();
  }

#pragma unroll
  for (int i = 0; i < 4; ++i) {
    int gr = row0 + ty * 4 + i;
    if (gr < M) {
      float di = dinv[gr];
#pragma unroll
      for (int j = 0; j < CN; j += 4) {
        *(float4*)&H[(size_t)gr * NC + tx * CN + j] =
            make_float4(di * acc[i][j], di * acc[i][j + 1],
                        di * acc[i][j + 2], di * acc[i][j + 3]);
      }
    }
  }
}

// ---- agg1: y[i] = relu( dinv_i * (h'_i + sum_src h'_src) + b1 ), 128 feats ----
__global__ __launch_bounds__(256) void agg1_k(const float2* __restrict__ hp,
                                              const float* __restrict__ dinv,
                                              const int* __restrict__ offsets,
                                              const int* __restrict__ csr_src,
                                              const float* __restrict__ b,
                                              float* __restrict__ y, int n) {
  int wave = threadIdx.x >> 6;
  int lane = threadIdx.x & 63;
  int node = blockIdx.x * NODES_PER_BLOCK + wave;
  if (node >= n) return;
  int beg = offsets[node], end = offsets[node + 1];
  int deg = end - beg;
  float2 self = hp[(size_t)node * 64 + lane];
  float ax = self.x, ay = self.y;
  int sv = 0;
  if (lane < deg) sv = csr_src[beg + lane];
  int lim = deg < 64 ? deg : 64;
  int e = 0;
  for (; e + 8 <= lim; e += 8) {
    int s0 = __shfl(sv, e + 0), s1 = __shfl(sv, e + 1);
    int s2 = __shfl(sv, e + 2), s3 = __shfl(sv, e + 3);
    int s4 = __shfl(sv, e + 4), s5 = __shfl(sv, e + 5);
    int s6 = __shfl(sv, e + 6), s7 = __shfl(sv, e + 7);
    float2 v0 = hp[(size_t)s0 * 64 + lane];
    float2 v1 = hp[(size_t)s1 * 64 + lane];
    float2 v2 = hp[(size_t)s2 * 64 + lane];
    float2 v3 = hp[(size_t)s3 * 64 + lane];
    float2 v4 = hp[(size_t)s4 * 64 + lane];
    float2 v5 = hp[(size_t)s5 * 64 + lane];
    float2 v6 = hp[(size_t)s6 * 64 + lane];
    float2 v7 = hp[(size_t)s7 * 64 + lane];
    ax += ((v0.x + v1.x) + (v2.x + v3.x)) + ((v4.x + v5.x) + (v6.x + v7.x));
    ay += ((v0.y + v1.y) + (v2.y + v3.y)) + ((v4.y + v5.y) + (v6.y + v7.y));
  }
  for (; e < lim; ++e) {
    int s = __shfl(sv, e);
    float2 v = hp[(size_t)s * 64 + lane];
    ax += v.x;
    ay += v.y;
  }
  for (int ee = beg + 64; ee < end; ++ee) {
    int s = csr_src[ee];
    float2 v = hp[(size_t)s * 64 + lane];
    ax += v.x;
    ay += v.y;
  }
  float di = dinv[node];
  float2 bb = ((const float2*)b)[lane];
  float2 o;
  o.x = fmaxf(fmaf(di, ax, bb.x), 0.0f);
  o.y = fmaxf(fmaf(di, ay, bb.y), 0.0f);
  ((float2*)y)[(size_t)node * 64 + lane] = o;
}

// ---- agg2: out[i] = dinv_i * (h'_i + sum_src h'_src) + b2, 64 feats ----
__global__ __launch_bounds__(256) void agg2_k(const float* __restrict__ hp,
                                              const float* __restrict__ dinv,
                                              const int* __restrict__ offsets,
                                              const int* __restrict__ csr_src,
                                              const float* __restrict__ b,
                                              float* __restrict__ out, int n) {
  int wave = threadIdx.x >> 6;
  int lane = threadIdx.x & 63;
  int node = blockIdx.x * NODES_PER_BLOCK + wave;
  if (node >= n) return;
  int beg = offsets[node], end = offsets[node + 1];
  int deg = end - beg;
  float acc = hp[(size_t)node * 64 + lane];
  int sv = 0;
  if (lane < deg) sv = csr_src[beg + lane];
  int lim = deg < 64 ? deg : 64;
  int e = 0;
  for (; e + 8 <= lim; e += 8) {
    int s0 = __shfl(sv, e + 0), s1 = __shfl(sv, e + 1);
    int s2 = __shfl(sv, e + 2), s3 = __shfl(sv, e + 3);
    int s4 = __shfl(sv, e + 4), s5 = __shfl(sv, e + 5);
    int s6 = __shfl(sv, e + 6), s7 = __shfl(sv, e + 7);
    float v0 = hp[(size_t)s0 * 64 + lane];
    float v1 = hp[(size_t)s1 * 64 + lane];
    float v2 = hp[(size_t)s2 * 64 + lane];
    float v3 = hp[(size_t)s3 * 64 + lane];
    float v4 = hp[(size_t)s4 * 64 + lane];
    float v5 = hp[(size_t)s5 * 64 + lane];
    float v6 = hp[(size_t)s6 * 64 + lane];
    float v7 = hp[(size_t)s7 * 64 + lane];
    acc += ((v0 + v1) + (v2 + v3)) + ((v4 + v5) + (v6 + v7));
  }
  for (; e < lim; ++e) {
    int s = __shfl(sv, e);
    acc += hp[(size_t)s * 64 + lane];
  }
  for (int ee = beg + 64; ee < end; ++ee) {
    acc += hp[(size_t)csr_src[ee] * 64 + lane];
  }
  float di = dinv[node];
  out[(size_t)node * 64 + lane] = fmaf(di, acc, b[lane]);
}

extern "C" void kernel_launch(void* const* d_in, const int* in_sizes, int n_in,
                              void* d_out, int out_size, void* d_ws, size_t ws_size,
                              hipStream_t stream) {
  const float* x  = (const float*)d_in[0];
  const int*   ei = (const int*)d_in[1];
  const float* W1 = (const float*)d_in[2];
  const float* b1 = (const float*)d_in[3];
  const float* W2 = (const float*)d_in[4];
  const float* b2 = (const float*)d_in[5];
  float* out = (float*)d_out;

  const int N = in_sizes[0] / 128;   // 50000
  const int E = in_sizes[1] / 2;     // 800000
  const int NBUCK = (N + 255) >> 8;             // 196
  const int NCHUNK = (E + CHUNK - 1) / CHUNK;   // 196

  char* w = (char*)d_ws;
  size_t off = 0;
  auto alloc = [&](size_t bytes) -> void* {
    void* p = w + off;
    off = (off + bytes + 511) & ~(size_t)511;
    return p;
  };
  int*   gh       = (int*)alloc((size_t)NBUCK * NCHUNK * 4);
  int*   totals   = (int*)alloc((size_t)NBUCK * 4);
  int*   bstart   = (int*)alloc((size_t)(NBUCK + 1) * 4);
  int*   flag     = (int*)alloc(64);
  int*   tmp      = (int*)alloc((size_t)E * 4);
  int*   offsets  = (int*)alloc((size_t)(N + 1) * 4);
  float* dinv     = (float*)alloc((size_t)N * 4);
  int*   csr_src  = (int*)alloc((size_t)E * 4);
  float* h1       = (float*)alloc((size_t)N * 128 * 4);
  float* y        = (float*)alloc((size_t)N * 128 * 4);
  float* h2       = (float*)alloc((size_t)N * 64 * 4);

  const int GB = (N + 63) / 64;
  const int AB = (N + NODES_PER_BLOCK - 1) / NODES_PER_BLOCK;

  detect64_k<<<1, 64, 0, stream>>>(ei, flag);
  hist_k<<<NCHUNK, 256, 0, stream>>>(ei, flag, gh, E, NCHUNK, NBUCK);
  tot_k<<<NBUCK, 256, 0, stream>>>(gh, totals, NCHUNK);
  scanrow_k<<<NBUCK, 256, 0, stream>>>(gh, totals, bstart, offsets, NCHUNK, NBUCK, N, E);
  part_k<<<NCHUNK, 256, 0, stream>>>(ei, flag, gh, tmp, E, NCHUNK, NBUCK);
  bucket_k<<<NBUCK, 256, 0, stream>>>(tmp, bstart, csr_src, offsets, dinv, N);

  gemm_k128<128><<<GB, 256, 0, stream>>>(x, W1, dinv, h1, N);
  agg1_k<<<AB, 256, 0, stream>>>((const float2*)h1, dinv, offsets, csr_src, b1, y, N);
  gemm_k128<64><<<GB, 256, 0, stream>>>(y, W2, dinv, h2, N);
  agg2_k<<<AB, 256, 0, stream>>>(h2, dinv, offsets, csr_src, b2, out, N);
}

// Round 6
// 159.149 us; speedup vs baseline: 2.0767x; 1.1391x over previous
//
#include <hip/hip_runtime.h>
#include <hip/hip_bf16.h>
#include <hip/hip_fp16.h>

// GCN 2-layer: N=50000 nodes, E=800000 edges, 128->128(relu)->64.
// CSR build via two-level LDS-binned partition (no global atomics).
// Layer 1: f32 GEMM + dinv-prescale stored as packed fp16x2; agg1 gathers fp16.
// Layer 2: pure f32 (round-4 structure, full-wave agg2).

#define NODES_PER_BLOCK 4
#define CHUNK 4096   // edges per partition chunk
#define BCAP 8192    // max edges per 256-node bucket held in LDS

typedef unsigned int uint;

__device__ __forceinline__ float2 h2f(uint v) {
  __half2 h;
  __builtin_memcpy(&h, &v, 4);
  return __half22float2(h);
}

__device__ __forceinline__ uint f2h(float a, float b) {
  __half2 h = __halves2half2(__float2half_rn(a), __float2half_rn(b));
  uint r;
  __builtin_memcpy(&r, &h, 4);
  return r;
}

// edge_index may arrive as int32 or int64 (word pairs). Values < 50000 =>
// int64 high words all zero.
__global__ void detect64_k(const int* ei, int* flag) {
  if (blockIdx.x == 0 && threadIdx.x == 0) {
    int z = 1;
    for (int i = 0; i < 64; ++i)
      if (ei[2 * i + 1] != 0) { z = 0; break; }
    *flag = z;
  }
}

// A1: per-chunk histogram over coarse buckets (dst >> 8)
__global__ __launch_bounds__(256) void hist_k(const int* __restrict__ ei,
                                              const int* __restrict__ flag,
                                              int* __restrict__ gh,
                                              int E, int nchunk, int nbuck) {
  __shared__ int h[256];
  int c = blockIdx.x;
  for (int i = threadIdx.x; i < 256; i += 256) h[i] = 0;
  __syncthreads();
  int is64 = *flag;
  int base = c * CHUNK;
  int lim = min(CHUNK, E - base);
  for (int i = threadIdx.x; i < lim; i += 256) {
    int e = base + i;
    int d = is64 ? ei[2 * ((size_t)E + e)] : ei[(size_t)E + e];
    atomicAdd(&h[d >> 8], 1);
  }
  __syncthreads();
  for (int k = threadIdx.x; k < nbuck; k += 256) gh[k * nchunk + c] = h[k];
}

// A2a: per-bucket totals
__global__ __launch_bounds__(256) void tot_k(const int* __restrict__ gh,
                                             int* __restrict__ totals, int nchunk) {
  __shared__ int sd[256];
  int k = blockIdx.x;
  int s = 0;
  for (int i = threadIdx.x; i < nchunk; i += 256) s += gh[k * nchunk + i];
  sd[threadIdx.x] = s;
  __syncthreads();
  for (int o = 128; o > 0; o >>= 1) {
    if (threadIdx.x < o) sd[threadIdx.x] += sd[threadIdx.x + o];
    __syncthreads();
  }
  if (threadIdx.x == 0) totals[k] = sd[0];
}

// A2c: block k: bucketStart[k] + in-place scan of gh row -> absolute bases.
__global__ __launch_bounds__(256) void scanrow_k(int* __restrict__ gh,
                                                 const int* __restrict__ totals,
                                                 int* __restrict__ bucketStart,
                                                 int* __restrict__ offsets,
                                                 int nchunk, int nbuck, int N, int E) {
  __shared__ int st[256];
  int k = blockIdx.x;
  int t = threadIdx.x;
  int v = (t < nbuck && t < k) ? totals[t] : 0;
  st[t] = v;
  __syncthreads();
  for (int o = 128; o > 0; o >>= 1) {
    if (t < o) st[t] += st[t + o];
    __syncthreads();
  }
  int bs = st[0];
  if (t == 0) {
    bucketStart[k] = bs;
    if (k == nbuck - 1) { bucketStart[nbuck] = E; offsets[N] = E; }
  }
  __syncthreads();
  int x = (t < nchunk) ? gh[k * nchunk + t] : 0;
  st[t] = x;
  __syncthreads();
  int incl = x;
  for (int o = 1; o < 256; o <<= 1) {
    int add = (t >= o) ? st[t - o] : 0;
    __syncthreads();
    incl += add;
    st[t] = incl;
    __syncthreads();
  }
  if (t < nchunk) gh[k * nchunk + t] = bs + (incl - x);
}

// A3: partition edges into bucket-grouped tmp, packed (src16 | dstlow8<<16)
__global__ __launch_bounds__(256) void part_k(const int* __restrict__ ei,
                                              const int* __restrict__ flag,
                                              const int* __restrict__ gh,
                                              int* __restrict__ tmp,
                                              int E, int nchunk, int nbuck) {
  __shared__ int cur[256];
  int c = blockIdx.x;
  for (int i = threadIdx.x; i < nbuck; i += 256) cur[i] = gh[i * nchunk + c];
  __syncthreads();
  int is64 = *flag;
  int base = c * CHUNK;
  int lim = min(CHUNK, E - base);
  for (int i = threadIdx.x; i < lim; i += 256) {
    int e = base + i;
    int s, d;
    if (is64) {
      s = ei[2 * (size_t)e];
      d = ei[2 * ((size_t)E + e)];
    } else {
      s = ei[e];
      d = ei[(size_t)E + e];
    }
    int p = atomicAdd(&cur[d >> 8], 1);
    tmp[p] = s | ((d & 255) << 16);
  }
}

// B: one block per bucket: LDS count+scan -> offsets, dinv, node-grouped csr_src
__global__ __launch_bounds__(256) void bucket_k(const int* __restrict__ tmp,
                                                const int* __restrict__ bucketStart,
                                                int* __restrict__ csr_src,
                                                int* __restrict__ offsets,
                                                float* __restrict__ dinv,
                                                int N) {
  __shared__ int ebuf[BCAP];
  __shared__ int cnt[256];
  __shared__ int st[256];
  __shared__ int lofs[256];
  int k = blockIdx.x;
  int b0 = bucketStart[k], b1 = bucketStart[k + 1];
  int sz = b1 - b0;
  int t = threadIdx.x;
  cnt[t] = 0;
  __syncthreads();
  bool inlds = (sz <= BCAP);
  if (inlds) {
    for (int i = t; i < sz; i += 256) {
      int v = tmp[b0 + i];
      ebuf[i] = v;
      atomicAdd(&cnt[v >> 16], 1);
    }
  } else {
    for (int i = t; i < sz; i += 256) atomicAdd(&cnt[tmp[b0 + i] >> 16], 1);
  }
  __syncthreads();
  int x = cnt[t];
  st[t] = x;
  __syncthreads();
  int incl = x;
  for (int o = 1; o < 256; o <<= 1) {
    int add = (t >= o) ? st[t - o] : 0;
    __syncthreads();
    incl += add;
    st[t] = incl;
    __syncthreads();
  }
  lofs[t] = incl - x;
  int node = k * 256 + t;
  if (node < N) {
    offsets[node] = b0 + lofs[t];
    dinv[node] = rsqrtf((float)(x + 1));  // +1 self-loop
  }
  __syncthreads();
  cnt[t] = lofs[t];  // reuse as cursor
  __syncthreads();
  if (inlds) {
    for (int i = t; i < sz; i += 256) {
      int v = ebuf[i];
      int p = atomicAdd(&cnt[v >> 16], 1);
      csr_src[b0 + p] = v & 0xFFFF;
    }
  } else {
    for (int i = t; i < sz; i += 256) {
      int v = tmp[b0 + i];
      int p = atomicAdd(&cnt[v >> 16], 1);
      csr_src[b0 + p] = v & 0xFFFF;
    }
  }
}

// ---- GEMM: H = dinv[row] * (X[M,128] @ W[128,NC]) ----
// NC=128: store packed fp16x2 (uint per 2 cols). NC=64: store f32.
template <int NC>
__global__ __launch_bounds__(256) void gemm_k128(const float* __restrict__ X,
                                                 const float* __restrict__ W,
                                                 const float* __restrict__ dinv,
                                                 void* __restrict__ Hout, int M) {
  constexpr int BK = 32;
  constexpr int CN = NC / 16;
  __shared__ float Xs[64][BK + 1];
  __shared__ float Ws[BK][NC];
  int tid = threadIdx.x;
  int tx = tid & 15;
  int ty = tid >> 4;
  int row0 = blockIdx.x * 64;

  float acc[4][CN];
#pragma unroll
  for (int i = 0; i < 4; ++i)
#pragma unroll
    for (int j = 0; j < CN; ++j) acc[i][j] = 0.0f;

  for (int k0 = 0; k0 < 128; k0 += BK) {
#pragma unroll
    for (int l = tid; l < 512; l += 256) {
      int r = l >> 3;
      int kq = (l & 7) * 4;
      int gr = row0 + r;
      float4 val;
      if (gr < M)
        val = *(const float4*)(X + (size_t)gr * 128 + k0 + kq);
      else
        val = make_float4(0.f, 0.f, 0.f, 0.f);
      Xs[r][kq + 0] = val.x;
      Xs[r][kq + 1] = val.y;
      Xs[r][kq + 2] = val.z;
      Xs[r][kq + 3] = val.w;
    }
    constexpr int WTOT = BK * NC / 4;
#pragma unroll
    for (int l = tid; l < WTOT; l += 256) {
      int kk = l / (NC / 4);
      int cq = (l % (NC / 4)) * 4;
      *(float4*)&Ws[kk][cq] = *(const float4*)(W + (size_t)(k0 + kk) * NC + cq);
    }
    __syncthreads();

#pragma unroll
    for (int kk = 0; kk < BK; ++kk) {
      float xv[4];
#pragma unroll
      for (int i = 0; i < 4; ++i) xv[i] = Xs[ty * 4 + i][kk];
      float wv[CN];
#pragma unroll
      for (int j = 0; j < CN; j += 4) {
        float4 wq = *(const float4*)&Ws[kk][tx * CN + j];
        wv[j + 0] = wq.x; wv[j + 1] = wq.y; wv[j + 2] = wq.z; wv[j + 3] = wq.w;
      }
#pragma unroll
      for (int i = 0; i < 4; ++i)
#pragma unroll
        for (int j = 0; j < CN; ++j) acc[i][j] = fmaf(xv[i], wv[j], acc[i][j]);
    }
    __syncthreads();
  }

#pragma unroll
  for (int i = 0; i < 4; ++i) {
    int gr = row0 + ty * 4 + i;
    if (gr < M) {
      float di = dinv[gr];
      if constexpr (NC == 128) {
        uint4 p;
        p.x = f2h(di * acc[i][0], di * acc[i][1]);
        p.y = f2h(di * acc[i][2], di * acc[i][3]);
        p.z = f2h(di * acc[i][4], di * acc[i][5]);
        p.w = f2h(di * acc[i][6], di * acc[i][7]);
        ((uint4*)Hout)[(size_t)gr * 16 + tx] = p;  // row = 64 uints = 16 uint4
      } else {
        float* H = (float*)Hout;
        *(float4*)&H[(size_t)gr * NC + tx * CN] =
            make_float4(di * acc[i][0], di * acc[i][1],
                        di * acc[i][2], di * acc[i][3]);
      }
    }
  }
}

// ---- agg1: y[i] = relu( dinv_i * (h'_i + sum_src h'_src) + b1 ), 128 feats ----
// h' rows: 64 uints (fp16x2) = 256B. Lane l holds feats 2l, 2l+1.
__global__ __launch_bounds__(256) void agg1_k(const uint* __restrict__ hp,
                                              const float* __restrict__ dinv,
                                              const int* __restrict__ offsets,
                                              const int* __restrict__ csr_src,
                                              const float* __restrict__ b,
                                              float* __restrict__ y, int n) {
  int wave = threadIdx.x >> 6;
  int lane = threadIdx.x & 63;
  int node = blockIdx.x * NODES_PER_BLOCK + wave;
  if (node >= n) return;
  int beg = offsets[node], end = offsets[node + 1];
  int deg = end - beg;
  float2 self = h2f(hp[(size_t)node * 64 + lane]);
  float ax = self.x, ay = self.y;
  int sv = 0;
  if (lane < deg) sv = csr_src[beg + lane];
  int lim = deg < 64 ? deg : 64;
  int e = 0;
  for (; e + 8 <= lim; e += 8) {
    int s0 = __shfl(sv, e + 0), s1 = __shfl(sv, e + 1);
    int s2 = __shfl(sv, e + 2), s3 = __shfl(sv, e + 3);
    int s4 = __shfl(sv, e + 4), s5 = __shfl(sv, e + 5);
    int s6 = __shfl(sv, e + 6), s7 = __shfl(sv, e + 7);
    uint u0 = hp[(size_t)s0 * 64 + lane];
    uint u1 = hp[(size_t)s1 * 64 + lane];
    uint u2 = hp[(size_t)s2 * 64 + lane];
    uint u3 = hp[(size_t)s3 * 64 + lane];
    uint u4 = hp[(size_t)s4 * 64 + lane];
    uint u5 = hp[(size_t)s5 * 64 + lane];
    uint u6 = hp[(size_t)s6 * 64 + lane];
    uint u7 = hp[(size_t)s7 * 64 + lane];
    float2 v0 = h2f(u0), v1 = h2f(u1), v2 = h2f(u2), v3 = h2f(u3);
    float2 v4 = h2f(u4), v5 = h2f(u5), v6 = h2f(u6), v7 = h2f(u7);
    ax += ((v0.x + v1.x) + (v2.x + v3.x)) + ((v4.x + v5.x) + (v6.x + v7.x));
    ay += ((v0.y + v1.y) + (v2.y + v3.y)) + ((v4.y + v5.y) + (v6.y + v7.y));
  }
  for (; e < lim; ++e) {
    int s = __shfl(sv, e);
    float2 v = h2f(hp[(size_t)s * 64 + lane]);
    ax += v.x;
    ay += v.y;
  }
  for (int ee = beg + 64; ee < end; ++ee) {  // deg>64 fallback
    float2 v = h2f(hp[(size_t)csr_src[ee] * 64 + lane]);
    ax += v.x;
    ay += v.y;
  }
  float di = dinv[node];
  float2 bb = ((const float2*)b)[lane];
  float2 o;
  o.x = fmaxf(fmaf(di, ax, bb.x), 0.0f);
  o.y = fmaxf(fmaf(di, ay, bb.y), 0.0f);
  ((float2*)y)[(size_t)node * 64 + lane] = o;
}

// ---- agg2: out[i] = dinv_i * (h'_i + sum_src h'_src) + b2, 64 feats, f32 ----
// (round-4 verbatim: full-wave, one f32 feature per lane)
__global__ __launch_bounds__(256) void agg2_k(const float* __restrict__ hp,
                                              const float* __restrict__ dinv,
                                              const int* __restrict__ offsets,
                                              const int* __restrict__ csr_src,
                                              const float* __restrict__ b,
                                              float* __restrict__ out, int n) {
  int wave = threadIdx.x >> 6;
  int lane = threadIdx.x & 63;
  int node = blockIdx.x * NODES_PER_BLOCK + wave;
  if (node >= n) return;
  int beg = offsets[node], end = offsets[node + 1];
  int deg = end - beg;
  float acc = hp[(size_t)node * 64 + lane];
  int sv = 0;
  if (lane < deg) sv = csr_src[beg + lane];
  int lim = deg < 64 ? deg : 64;
  int e = 0;
  for (; e + 8 <= lim; e += 8) {
    int s0 = __shfl(sv, e + 0), s1 = __shfl(sv, e + 1);
    int s2 = __shfl(sv, e + 2), s3 = __shfl(sv, e + 3);
    int s4 = __shfl(sv, e + 4), s5 = __shfl(sv, e + 5);
    int s6 = __shfl(sv, e + 6), s7 = __shfl(sv, e + 7);
    float v0 = hp[(size_t)s0 * 64 + lane];
    float v1 = hp[(size_t)s1 * 64 + lane];
    float v2 = hp[(size_t)s2 * 64 + lane];
    float v3 = hp[(size_t)s3 * 64 + lane];
    float v4 = hp[(size_t)s4 * 64 + lane];
    float v5 = hp[(size_t)s5 * 64 + lane];
    float v6 = hp[(size_t)s6 * 64 + lane];
    float v7 = hp[(size_t)s7 * 64 + lane];
    acc += ((v0 + v1) + (v2 + v3)) + ((v4 + v5) + (v6 + v7));
  }
  for (; e < lim; ++e) {
    int s = __shfl(sv, e);
    acc += hp[(size_t)s * 64 + lane];
  }
  for (int ee = beg + 64; ee < end; ++ee) {
    acc += hp[(size_t)csr_src[ee] * 64 + lane];
  }
  float di = dinv[node];
  out[(size_t)node * 64 + lane] = fmaf(di, acc, b[lane]);
}

extern "C" void kernel_launch(void* const* d_in, const int* in_sizes, int n_in,
                              void* d_out, int out_size, void* d_ws, size_t ws_size,
                              hipStream_t stream) {
  const float* x  = (const float*)d_in[0];
  const int*   ei = (const int*)d_in[1];
  const float* W1 = (const float*)d_in[2];
  const float* b1 = (const float*)d_in[3];
  const float* W2 = (const float*)d_in[4];
  const float* b2 = (const float*)d_in[5];
  float* out = (float*)d_out;

  const int N = in_sizes[0] / 128;   // 50000
  const int E = in_sizes[1] / 2;     // 800000
  const int NBUCK = (N + 255) >> 8;             // 196
  const int NCHUNK = (E + CHUNK - 1) / CHUNK;   // 196

  char* w = (char*)d_ws;
  size_t off = 0;
  auto alloc = [&](size_t bytes) -> void* {
    void* p = w + off;
    off = (off + bytes + 511) & ~(size_t)511;
    return p;
  };
  int*   gh       = (int*)alloc((size_t)NBUCK * NCHUNK * 4);
  int*   totals   = (int*)alloc((size_t)NBUCK * 4);
  int*   bstart   = (int*)alloc((size_t)(NBUCK + 1) * 4);
  int*   flag     = (int*)alloc(64);
  int*   tmp      = (int*)alloc((size_t)E * 4);
  int*   offsets  = (int*)alloc((size_t)(N + 1) * 4);
  float* dinv     = (float*)alloc((size_t)N * 4);
  int*   csr_src  = (int*)alloc((size_t)E * 4);
  uint*  h1       = (uint*)alloc((size_t)N * 64 * 4);   // fp16x2 [N][64]
  float* y        = (float*)alloc((size_t)N * 128 * 4); // relu output f32
  float* h2       = (float*)alloc((size_t)N * 64 * 4);  // f32 [N][64]

  const int GB = (N + 63) / 64;
  const int AB = (N + NODES_PER_BLOCK - 1) / NODES_PER_BLOCK;

  detect64_k<<<1, 64, 0, stream>>>(ei, flag);
  hist_k<<<NCHUNK, 256, 0, stream>>>(ei, flag, gh, E, NCHUNK, NBUCK);
  tot_k<<<NBUCK, 256, 0, stream>>>(gh, totals, NCHUNK);
  scanrow_k<<<NBUCK, 256, 0, stream>>>(gh, totals, bstart, offsets, NCHUNK, NBUCK, N, E);
  part_k<<<NCHUNK, 256, 0, stream>>>(ei, flag, gh, tmp, E, NCHUNK, NBUCK);
  bucket_k<<<NBUCK, 256, 0, stream>>>(tmp, bstart, csr_src, offsets, dinv, N);

  gemm_k128<128><<<GB, 256, 0, stream>>>(x, W1, dinv, h1, N);
  agg1_k<<<AB, 256, 0, stream>>>(h1, dinv, offsets, csr_src, b1, y, N);
  gemm_k128<64><<<GB, 256, 0, stream>>>(y, W2, dinv, h2, N);
  agg2_k<<<AB, 256, 0, stream>>>(h2, dinv, offsets, csr_src, b2, out, N);
}

// Round 7
// 132.948 us; speedup vs baseline: 2.4860x; 1.1971x over previous
//
#include <hip/hip_runtime.h>
#include <hip/hip_bf16.h>
#include <hip/hip_fp16.h>

// GCN 2-layer: N=50000 nodes, E=800000 edges, 128->128(relu)->64.
// CSR build via two-level LDS-binned partition (no global atomics).
// GEMMs: fp16 MFMA (16x16x32), LDS-free: A from global f32+cvt, B from
// fragment-linear packed fp16 (prep_k), f32 accum, dinv-scaled epilogue.
// agg1 gathers fp16 rows; layer 2 f32 (full-wave agg2).

#define NODES_PER_BLOCK 4
#define CHUNK 4096   // edges per partition chunk
#define BCAP 8192    // max edges per 256-node bucket held in LDS

typedef unsigned int uint;
typedef _Float16 f16x8 __attribute__((ext_vector_type(8)));
typedef float f32x4 __attribute__((ext_vector_type(4)));

__device__ __forceinline__ float2 h2f(uint v) {
  __half2 h;
  __builtin_memcpy(&h, &v, 4);
  return __half22float2(h);
}

// edge_index may arrive as int32 or int64 (word pairs). Values < 50000 =>
// int64 high words all zero.
__global__ void detect64_k(const int* ei, int* flag) {
  if (blockIdx.x == 0 && threadIdx.x == 0) {
    int z = 1;
    for (int i = 0; i < 64; ++i)
      if (ei[2 * i + 1] != 0) { z = 0; break; }
    *flag = z;
  }
}

// A1: per-chunk histogram over coarse buckets (dst >> 8)
__global__ __launch_bounds__(256) void hist_k(const int* __restrict__ ei,
                                              const int* __restrict__ flag,
                                              int* __restrict__ gh,
                                              int E, int nchunk, int nbuck) {
  __shared__ int h[256];
  int c = blockIdx.x;
  for (int i = threadIdx.x; i < 256; i += 256) h[i] = 0;
  __syncthreads();
  int is64 = *flag;
  int base = c * CHUNK;
  int lim = min(CHUNK, E - base);
  for (int i = threadIdx.x; i < lim; i += 256) {
    int e = base + i;
    int d = is64 ? ei[2 * ((size_t)E + e)] : ei[(size_t)E + e];
    atomicAdd(&h[d >> 8], 1);
  }
  __syncthreads();
  for (int k = threadIdx.x; k < nbuck; k += 256) gh[k * nchunk + c] = h[k];
}

// A2a: per-bucket totals
__global__ __launch_bounds__(256) void tot_k(const int* __restrict__ gh,
                                             int* __restrict__ totals, int nchunk) {
  __shared__ int sd[256];
  int k = blockIdx.x;
  int s = 0;
  for (int i = threadIdx.x; i < nchunk; i += 256) s += gh[k * nchunk + i];
  sd[threadIdx.x] = s;
  __syncthreads();
  for (int o = 128; o > 0; o >>= 1) {
    if (threadIdx.x < o) sd[threadIdx.x] += sd[threadIdx.x + o];
    __syncthreads();
  }
  if (threadIdx.x == 0) totals[k] = sd[0];
}

// A2c: block k: bucketStart[k] + in-place scan of gh row -> absolute bases.
__global__ __launch_bounds__(256) void scanrow_k(int* __restrict__ gh,
                                                 const int* __restrict__ totals,
                                                 int* __restrict__ bucketStart,
                                                 int* __restrict__ offsets,
                                                 int nchunk, int nbuck, int N, int E) {
  __shared__ int st[256];
  int k = blockIdx.x;
  int t = threadIdx.x;
  int v = (t < nbuck && t < k) ? totals[t] : 0;
  st[t] = v;
  __syncthreads();
  for (int o = 128; o > 0; o >>= 1) {
    if (t < o) st[t] += st[t + o];
    __syncthreads();
  }
  int bs = st[0];
  if (t == 0) {
    bucketStart[k] = bs;
    if (k == nbuck - 1) { bucketStart[nbuck] = E; offsets[N] = E; }
  }
  __syncthreads();
  int x = (t < nchunk) ? gh[k * nchunk + t] : 0;
  st[t] = x;
  __syncthreads();
  int incl = x;
  for (int o = 1; o < 256; o <<= 1) {
    int add = (t >= o) ? st[t - o] : 0;
    __syncthreads();
    incl += add;
    st[t] = incl;
    __syncthreads();
  }
  if (t < nchunk) gh[k * nchunk + t] = bs + (incl - x);
}

// A3: partition edges into bucket-grouped tmp, packed (src16 | dstlow8<<16)
__global__ __launch_bounds__(256) void part_k(const int* __restrict__ ei,
                                              const int* __restrict__ flag,
                                              const int* __restrict__ gh,
                                              int* __restrict__ tmp,
                                              int E, int nchunk, int nbuck) {
  __shared__ int cur[256];
  int c = blockIdx.x;
  for (int i = threadIdx.x; i < nbuck; i += 256) cur[i] = gh[i * nchunk + c];
  __syncthreads();
  int is64 = *flag;
  int base = c * CHUNK;
  int lim = min(CHUNK, E - base);
  for (int i = threadIdx.x; i < lim; i += 256) {
    int e = base + i;
    int s, d;
    if (is64) {
      s = ei[2 * (size_t)e];
      d = ei[2 * ((size_t)E + e)];
    } else {
      s = ei[e];
      d = ei[(size_t)E + e];
    }
    int p = atomicAdd(&cur[d >> 8], 1);
    tmp[p] = s | ((d & 255) << 16);
  }
}

// B: one block per bucket: LDS count+scan -> offsets, dinv, node-grouped csr_src
__global__ __launch_bounds__(256) void bucket_k(const int* __restrict__ tmp,
                                                const int* __restrict__ bucketStart,
                                                int* __restrict__ csr_src,
                                                int* __restrict__ offsets,
                                                float* __restrict__ dinv,
                                                int N) {
  __shared__ int ebuf[BCAP];
  __shared__ int cnt[256];
  __shared__ int st[256];
  __shared__ int lofs[256];
  int k = blockIdx.x;
  int b0 = bucketStart[k], b1 = bucketStart[k + 1];
  int sz = b1 - b0;
  int t = threadIdx.x;
  cnt[t] = 0;
  __syncthreads();
  bool inlds = (sz <= BCAP);
  if (inlds) {
    for (int i = t; i < sz; i += 256) {
      int v = tmp[b0 + i];
      ebuf[i] = v;
      atomicAdd(&cnt[v >> 16], 1);
    }
  } else {
    for (int i = t; i < sz; i += 256) atomicAdd(&cnt[tmp[b0 + i] >> 16], 1);
  }
  __syncthreads();
  int x = cnt[t];
  st[t] = x;
  __syncthreads();
  int incl = x;
  for (int o = 1; o < 256; o <<= 1) {
    int add = (t >= o) ? st[t - o] : 0;
    __syncthreads();
    incl += add;
    st[t] = incl;
    __syncthreads();
  }
  lofs[t] = incl - x;
  int node = k * 256 + t;
  if (node < N) {
    offsets[node] = b0 + lofs[t];
    dinv[node] = rsqrtf((float)(x + 1));  // +1 self-loop
  }
  __syncthreads();
  cnt[t] = lofs[t];  // reuse as cursor
  __syncthreads();
  if (inlds) {
    for (int i = t; i < sz; i += 256) {
      int v = ebuf[i];
      int p = atomicAdd(&cnt[v >> 16], 1);
      csr_src[b0 + p] = v & 0xFFFF;
    }
  } else {
    for (int i = t; i < sz; i += 256) {
      int v = tmp[b0 + i];
      int p = atomicAdd(&cnt[v >> 16], 1);
      csr_src[b0 + p] = v & 0xFFFF;
    }
  }
}

// ---- prep: W[K=128][NC] f32 -> fragment-linear fp16 pack ----
// P[(((t*NF + c)*64 + l)*8 + j)] = fp16( W[t*32 + (l>>4)*8 + j][c*16 + (l&15)] )
__global__ void prep_k(const float* __restrict__ W, _Float16* __restrict__ P,
                       int NC, int total) {
  int idx = blockIdx.x * blockDim.x + threadIdx.x;
  if (idx >= total) return;
  int NF = NC >> 4;
  int j = idx & 7;
  int l = (idx >> 3) & 63;
  int rest = idx >> 9;
  int c = rest % NF;
  int t = rest / NF;
  int k = t * 32 + ((l >> 4) << 3) + j;
  int col = c * 16 + (l & 15);
  P[idx] = (_Float16)W[(size_t)k * NC + col];
}

// ---- MFMA GEMM: H = dinv[row] * (X[M,128] @ W[128,NC]) ----
// 4 waves/block, wave w: rows blk*64 + w*16. No LDS.
// NC=128: store fp16 row-major. NC=64: store f32 row-major.
template <int NC>
__global__ __launch_bounds__(256) void mfma_gemm_k(const float* __restrict__ X,
                                                   const _Float16* __restrict__ Wp,
                                                   const float* __restrict__ dinv,
                                                   void* __restrict__ Hout, int M) {
  constexpr int NF = NC / 16;
  int lane = threadIdx.x & 63;
  int w = threadIdx.x >> 6;
  int row0 = blockIdx.x * 64 + w * 16;
  int arow = row0 + (lane & 15);
  bool av = arow < M;
  const float* xr = X + (size_t)arow * 128 + ((lane >> 4) << 3);
  const uint4* wp = (const uint4*)Wp;

  f32x4 acc[NF];
#pragma unroll
  for (int c = 0; c < NF; ++c) acc[c] = (f32x4){0.f, 0.f, 0.f, 0.f};

#pragma unroll
  for (int t = 0; t < 4; ++t) {
    float4 lo = av ? *(const float4*)(xr + t * 32)
                   : make_float4(0.f, 0.f, 0.f, 0.f);
    float4 hi = av ? *(const float4*)(xr + t * 32 + 4)
                   : make_float4(0.f, 0.f, 0.f, 0.f);
    f16x8 a;
    a[0] = (_Float16)lo.x; a[1] = (_Float16)lo.y;
    a[2] = (_Float16)lo.z; a[3] = (_Float16)lo.w;
    a[4] = (_Float16)hi.x; a[5] = (_Float16)hi.y;
    a[6] = (_Float16)hi.z; a[7] = (_Float16)hi.w;
#pragma unroll
    for (int c = 0; c < NF; ++c) {
      uint4 braw = wp[(t * NF + c) * 64 + lane];
      f16x8 b;
      __builtin_memcpy(&b, &braw, 16);
      acc[c] = __builtin_amdgcn_mfma_f32_16x16x32_f16(a, b, acc[c], 0, 0, 0);
    }
  }

  int rbase = row0 + ((lane >> 4) << 2);
#pragma unroll
  for (int r = 0; r < 4; ++r) {
    int row = rbase + r;
    if (row < M) {
      float di = dinv[row];
      if constexpr (NC == 128) {
        _Float16* H = (_Float16*)Hout;
#pragma unroll
        for (int c = 0; c < NF; ++c)
          H[(size_t)row * 128 + c * 16 + (lane & 15)] = (_Float16)(di * acc[c][r]);
      } else {
        float* H = (float*)Hout;
#pragma unroll
        for (int c = 0; c < NF; ++c)
          H[(size_t)row * 64 + c * 16 + (lane & 15)] = di * acc[c][r];
      }
    }
  }
}

// ---- agg1: y[i] = relu( dinv_i * (h'_i + sum_src h'_src) + b1 ), 128 feats ----
// h' rows: 64 uints (fp16x2) = 256B. Lane l holds feats 2l, 2l+1.
__global__ __launch_bounds__(256) void agg1_k(const uint* __restrict__ hp,
                                              const float* __restrict__ dinv,
                                              const int* __restrict__ offsets,
                                              const int* __restrict__ csr_src,
                                              const float* __restrict__ b,
                                              float* __restrict__ y, int n) {
  int wave = threadIdx.x >> 6;
  int lane = threadIdx.x & 63;
  int node = blockIdx.x * NODES_PER_BLOCK + wave;
  if (node >= n) return;
  int beg = offsets[node], end = offsets[node + 1];
  int deg = end - beg;
  float2 self = h2f(hp[(size_t)node * 64 + lane]);
  float ax = self.x, ay = self.y;
  int sv = 0;
  if (lane < deg) sv = csr_src[beg + lane];
  int lim = deg < 64 ? deg : 64;
  int e = 0;
  for (; e + 8 <= lim; e += 8) {
    int s0 = __shfl(sv, e + 0), s1 = __shfl(sv, e + 1);
    int s2 = __shfl(sv, e + 2), s3 = __shfl(sv, e + 3);
    int s4 = __shfl(sv, e + 4), s5 = __shfl(sv, e + 5);
    int s6 = __shfl(sv, e + 6), s7 = __shfl(sv, e + 7);
    uint u0 = hp[(size_t)s0 * 64 + lane];
    uint u1 = hp[(size_t)s1 * 64 + lane];
    uint u2 = hp[(size_t)s2 * 64 + lane];
    uint u3 = hp[(size_t)s3 * 64 + lane];
    uint u4 = hp[(size_t)s4 * 64 + lane];
    uint u5 = hp[(size_t)s5 * 64 + lane];
    uint u6 = hp[(size_t)s6 * 64 + lane];
    uint u7 = hp[(size_t)s7 * 64 + lane];
    float2 v0 = h2f(u0), v1 = h2f(u1), v2 = h2f(u2), v3 = h2f(u3);
    float2 v4 = h2f(u4), v5 = h2f(u5), v6 = h2f(u6), v7 = h2f(u7);
    ax += ((v0.x + v1.x) + (v2.x + v3.x)) + ((v4.x + v5.x) + (v6.x + v7.x));
    ay += ((v0.y + v1.y) + (v2.y + v3.y)) + ((v4.y + v5.y) + (v6.y + v7.y));
  }
  for (; e < lim; ++e) {
    int s = __shfl(sv, e);
    float2 v = h2f(hp[(size_t)s * 64 + lane]);
    ax += v.x;
    ay += v.y;
  }
  for (int ee = beg + 64; ee < end; ++ee) {  // deg>64 fallback
    float2 v = h2f(hp[(size_t)csr_src[ee] * 64 + lane]);
    ax += v.x;
    ay += v.y;
  }
  float di = dinv[node];
  float2 bb = ((const float2*)b)[lane];
  float2 o;
  o.x = fmaxf(fmaf(di, ax, bb.x), 0.0f);
  o.y = fmaxf(fmaf(di, ay, bb.y), 0.0f);
  ((float2*)y)[(size_t)node * 64 + lane] = o;
}

// ---- agg2: out[i] = dinv_i * (h'_i + sum_src h'_src) + b2, 64 feats, f32 ----
__global__ __launch_bounds__(256) void agg2_k(const float* __restrict__ hp,
                                              const float* __restrict__ dinv,
                                              const int* __restrict__ offsets,
                                              const int* __restrict__ csr_src,
                                              const float* __restrict__ b,
                                              float* __restrict__ out, int n) {
  int wave = threadIdx.x >> 6;
  int lane = threadIdx.x & 63;
  int node = blockIdx.x * NODES_PER_BLOCK + wave;
  if (node >= n) return;
  int beg = offsets[node], end = offsets[node + 1];
  int deg = end - beg;
  float acc = hp[(size_t)node * 64 + lane];
  int sv = 0;
  if (lane < deg) sv = csr_src[beg + lane];
  int lim = deg < 64 ? deg : 64;
  int e = 0;
  for (; e + 8 <= lim; e += 8) {
    int s0 = __shfl(sv, e + 0), s1 = __shfl(sv, e + 1);
    int s2 = __shfl(sv, e + 2), s3 = __shfl(sv, e + 3);
    int s4 = __shfl(sv, e + 4), s5 = __shfl(sv, e + 5);
    int s6 = __shfl(sv, e + 6), s7 = __shfl(sv, e + 7);
    float v0 = hp[(size_t)s0 * 64 + lane];
    float v1 = hp[(size_t)s1 * 64 + lane];
    float v2 = hp[(size_t)s2 * 64 + lane];
    float v3 = hp[(size_t)s3 * 64 + lane];
    float v4 = hp[(size_t)s4 * 64 + lane];
    float v5 = hp[(size_t)s5 * 64 + lane];
    float v6 = hp[(size_t)s6 * 64 + lane];
    float v7 = hp[(size_t)s7 * 64 + lane];
    acc += ((v0 + v1) + (v2 + v3)) + ((v4 + v5) + (v6 + v7));
  }
  for (; e < lim; ++e) {
    int s = __shfl(sv, e);
    acc += hp[(size_t)s * 64 + lane];
  }
  for (int ee = beg + 64; ee < end; ++ee) {
    acc += hp[(size_t)csr_src[ee] * 64 + lane];
  }
  float di = dinv[node];
  out[(size_t)node * 64 + lane] = fmaf(di, acc, b[lane]);
}

extern "C" void kernel_launch(void* const* d_in, const int* in_sizes, int n_in,
                              void* d_out, int out_size, void* d_ws, size_t ws_size,
                              hipStream_t stream) {
  const float* x  = (const float*)d_in[0];
  const int*   ei = (const int*)d_in[1];
  const float* W1 = (const float*)d_in[2];
  const float* b1 = (const float*)d_in[3];
  const float* W2 = (const float*)d_in[4];
  const float* b2 = (const float*)d_in[5];
  float* out = (float*)d_out;

  const int N = in_sizes[0] / 128;   // 50000
  const int E = in_sizes[1] / 2;     // 800000
  const int NBUCK = (N + 255) >> 8;             // 196
  const int NCHUNK = (E + CHUNK - 1) / CHUNK;   // 196

  char* w = (char*)d_ws;
  size_t off = 0;
  auto alloc = [&](size_t bytes) -> void* {
    void* p = w + off;
    off = (off + bytes + 511) & ~(size_t)511;
    return p;
  };
  int*       gh      = (int*)alloc((size_t)NBUCK * NCHUNK * 4);
  int*       totals  = (int*)alloc((size_t)NBUCK * 4);
  int*       bstart  = (int*)alloc((size_t)(NBUCK + 1) * 4);
  int*       flag    = (int*)alloc(64);
  int*       tmp     = (int*)alloc((size_t)E * 4);
  int*       offsets = (int*)alloc((size_t)(N + 1) * 4);
  float*     dinv    = (float*)alloc((size_t)N * 4);
  int*       csr_src = (int*)alloc((size_t)E * 4);
  _Float16*  pW1     = (_Float16*)alloc(16384 * 2);
  _Float16*  pW2     = (_Float16*)alloc(8192 * 2);
  _Float16*  h1      = (_Float16*)alloc((size_t)N * 128 * 2);  // fp16 [N][128]
  float*     y       = (float*)alloc((size_t)N * 128 * 4);     // relu out f32
  float*     h2      = (float*)alloc((size_t)N * 64 * 4);      // f32 [N][64]

  const int GB = (N + 63) / 64;
  const int AB = (N + NODES_PER_BLOCK - 1) / NODES_PER_BLOCK;

  detect64_k<<<1, 64, 0, stream>>>(ei, flag);
  hist_k<<<NCHUNK, 256, 0, stream>>>(ei, flag, gh, E, NCHUNK, NBUCK);
  tot_k<<<NBUCK, 256, 0, stream>>>(gh, totals, NCHUNK);
  scanrow_k<<<NBUCK, 256, 0, stream>>>(gh, totals, bstart, offsets, NCHUNK, NBUCK, N, E);
  part_k<<<NCHUNK, 256, 0, stream>>>(ei, flag, gh, tmp, E, NCHUNK, NBUCK);
  bucket_k<<<NBUCK, 256, 0, stream>>>(tmp, bstart, csr_src, offsets, dinv, N);

  prep_k<<<64, 256, 0, stream>>>(W1, pW1, 128, 16384);
  prep_k<<<32, 256, 0, stream>>>(W2, pW2, 64, 8192);

  mfma_gemm_k<128><<<GB, 256, 0, stream>>>(x, pW1, dinv, h1, N);
  agg1_k<<<AB, 256, 0, stream>>>((const uint*)h1, dinv, offsets, csr_src, b1, y, N);
  mfma_gemm_k<64><<<GB, 256, 0, stream>>>(y, pW2, dinv, h2, N);
  agg2_k<<<AB, 256, 0, stream>>>(h2, dinv, offsets, csr_src, b2, out, N);
}

// Round 8
// 117.966 us; speedup vs baseline: 2.8018x; 1.1270x over previous
//
#include <hip/hip_runtime.h>
#include <hip/hip_bf16.h>
#include <hip/hip_fp16.h>

// GCN 2-layer: N=50000 nodes, E=800000 edges, 128->128(relu)->64.
// CSR build via two-level LDS-binned partition (no global atomics).
// GEMMs: fp16 MFMA (16x16x32), LDS-free; fp16 payloads end-to-end
// (h1, y, h2 all fp16; accumulation f32). agg2: one 32-lane segment
// per node with width-32 shuffles (segment-uniform trip counts).

#define NODES_PER_BLOCK 4
#define CHUNK 4096   // edges per partition chunk
#define BCAP 8192    // max edges per 256-node bucket held in LDS

typedef unsigned int uint;
typedef _Float16 f16x8 __attribute__((ext_vector_type(8)));
typedef float f32x4 __attribute__((ext_vector_type(4)));

__device__ __forceinline__ float2 h2f(uint v) {
  __half2 h;
  __builtin_memcpy(&h, &v, 4);
  return __half22float2(h);
}

__device__ __forceinline__ uint f2h(float a, float b) {
  __half2 h = __halves2half2(__float2half_rn(a), __float2half_rn(b));
  uint r;
  __builtin_memcpy(&r, &h, 4);
  return r;
}

// edge_index may arrive as int32 or int64 (word pairs). Values < 50000 =>
// int64 high words all zero. Parallel: 64 lanes + ballot (no serial chain).
__global__ void detect64_k(const int* ei, int* flag) {
  int lane = threadIdx.x & 63;
  unsigned long long m = __ballot(ei[2 * lane + 1] != 0);
  if (threadIdx.x == 0) *flag = (m == 0ULL) ? 1 : 0;
}

// A1: per-chunk histogram over coarse buckets (dst >> 8)
__global__ __launch_bounds__(256) void hist_k(const int* __restrict__ ei,
                                              const int* __restrict__ flag,
                                              int* __restrict__ gh,
                                              int E, int nchunk, int nbuck) {
  __shared__ int h[256];
  int c = blockIdx.x;
  for (int i = threadIdx.x; i < 256; i += 256) h[i] = 0;
  __syncthreads();
  int is64 = *flag;
  int base = c * CHUNK;
  int lim = min(CHUNK, E - base);
  for (int i = threadIdx.x; i < lim; i += 256) {
    int e = base + i;
    int d = is64 ? ei[2 * ((size_t)E + e)] : ei[(size_t)E + e];
    atomicAdd(&h[d >> 8], 1);
  }
  __syncthreads();
  for (int k = threadIdx.x; k < nbuck; k += 256) gh[k * nchunk + c] = h[k];
}

// A2a: per-bucket totals
__global__ __launch_bounds__(256) void tot_k(const int* __restrict__ gh,
                                             int* __restrict__ totals, int nchunk) {
  __shared__ int sd[256];
  int k = blockIdx.x;
  int s = 0;
  for (int i = threadIdx.x; i < nchunk; i += 256) s += gh[k * nchunk + i];
  sd[threadIdx.x] = s;
  __syncthreads();
  for (int o = 128; o > 0; o >>= 1) {
    if (threadIdx.x < o) sd[threadIdx.x] += sd[threadIdx.x + o];
    __syncthreads();
  }
  if (threadIdx.x == 0) totals[k] = sd[0];
}

// A2c: block k: bucketStart[k] + in-place scan of gh row -> absolute bases.
__global__ __launch_bounds__(256) void scanrow_k(int* __restrict__ gh,
                                                 const int* __restrict__ totals,
                                                 int* __restrict__ bucketStart,
                                                 int* __restrict__ offsets,
                                                 int nchunk, int nbuck, int N, int E) {
  __shared__ int st[256];
  int k = blockIdx.x;
  int t = threadIdx.x;
  int v = (t < nbuck && t < k) ? totals[t] : 0;
  st[t] = v;
  __syncthreads();
  for (int o = 128; o > 0; o >>= 1) {
    if (t < o) st[t] += st[t + o];
    __syncthreads();
  }
  int bs = st[0];
  if (t == 0) {
    bucketStart[k] = bs;
    if (k == nbuck - 1) { bucketStart[nbuck] = E; offsets[N] = E; }
  }
  __syncthreads();
  int x = (t < nchunk) ? gh[k * nchunk + t] : 0;
  st[t] = x;
  __syncthreads();
  int incl = x;
  for (int o = 1; o < 256; o <<= 1) {
    int add = (t >= o) ? st[t - o] : 0;
    __syncthreads();
    incl += add;
    st[t] = incl;
    __syncthreads();
  }
  if (t < nchunk) gh[k * nchunk + t] = bs + (incl - x);
}

// A3: partition edges into bucket-grouped tmp, packed (src16 | dstlow8<<16)
__global__ __launch_bounds__(256) void part_k(const int* __restrict__ ei,
                                              const int* __restrict__ flag,
                                              const int* __restrict__ gh,
                                              int* __restrict__ tmp,
                                              int E, int nchunk, int nbuck) {
  __shared__ int cur[256];
  int c = blockIdx.x;
  for (int i = threadIdx.x; i < nbuck; i += 256) cur[i] = gh[i * nchunk + c];
  __syncthreads();
  int is64 = *flag;
  int base = c * CHUNK;
  int lim = min(CHUNK, E - base);
  for (int i = threadIdx.x; i < lim; i += 256) {
    int e = base + i;
    int s, d;
    if (is64) {
      s = ei[2 * (size_t)e];
      d = ei[2 * ((size_t)E + e)];
    } else {
      s = ei[e];
      d = ei[(size_t)E + e];
    }
    int p = atomicAdd(&cur[d >> 8], 1);
    tmp[p] = s | ((d & 255) << 16);
  }
}

// B: one block per bucket: LDS count+scan -> offsets, dinv, node-grouped csr_src
__global__ __launch_bounds__(256) void bucket_k(const int* __restrict__ tmp,
                                                const int* __restrict__ bucketStart,
                                                int* __restrict__ csr_src,
                                                int* __restrict__ offsets,
                                                float* __restrict__ dinv,
                                                int N) {
  __shared__ int ebuf[BCAP];
  __shared__ int cnt[256];
  __shared__ int st[256];
  __shared__ int lofs[256];
  int k = blockIdx.x;
  int b0 = bucketStart[k], b1 = bucketStart[k + 1];
  int sz = b1 - b0;
  int t = threadIdx.x;
  cnt[t] = 0;
  __syncthreads();
  bool inlds = (sz <= BCAP);
  if (inlds) {
    for (int i = t; i < sz; i += 256) {
      int v = tmp[b0 + i];
      ebuf[i] = v;
      atomicAdd(&cnt[v >> 16], 1);
    }
  } else {
    for (int i = t; i < sz; i += 256) atomicAdd(&cnt[tmp[b0 + i] >> 16], 1);
  }
  __syncthreads();
  int x = cnt[t];
  st[t] = x;
  __syncthreads();
  int incl = x;
  for (int o = 1; o < 256; o <<= 1) {
    int add = (t >= o) ? st[t - o] : 0;
    __syncthreads();
    incl += add;
    st[t] = incl;
    __syncthreads();
  }
  lofs[t] = incl - x;
  int node = k * 256 + t;
  if (node < N) {
    offsets[node] = b0 + lofs[t];
    dinv[node] = rsqrtf((float)(x + 1));  // +1 self-loop
  }
  __syncthreads();
  cnt[t] = lofs[t];  // reuse as cursor
  __syncthreads();
  if (inlds) {
    for (int i = t; i < sz; i += 256) {
      int v = ebuf[i];
      int p = atomicAdd(&cnt[v >> 16], 1);
      csr_src[b0 + p] = v & 0xFFFF;
    }
  } else {
    for (int i = t; i < sz; i += 256) {
      int v = tmp[b0 + i];
      int p = atomicAdd(&cnt[v >> 16], 1);
      csr_src[b0 + p] = v & 0xFFFF;
    }
  }
}

// ---- prep: W[K=128][NC] f32 -> fragment-linear fp16 pack ----
// P[(((t*NF + c)*64 + l)*8 + j)] = fp16( W[t*32 + (l>>4)*8 + j][c*16 + (l&15)] )
__global__ void prep_k(const float* __restrict__ W, _Float16* __restrict__ P,
                       int NC, int total) {
  int idx = blockIdx.x * blockDim.x + threadIdx.x;
  if (idx >= total) return;
  int NF = NC >> 4;
  int j = idx & 7;
  int l = (idx >> 3) & 63;
  int rest = idx >> 9;
  int c = rest % NF;
  int t = rest / NF;
  int k = t * 32 + ((l >> 4) << 3) + j;
  int col = c * 16 + (l & 15);
  P[idx] = (_Float16)W[(size_t)k * NC + col];
}

// ---- MFMA GEMM: H(fp16) = dinv[row] * (X[M,128] @ W[128,NC]) ----
// 4 waves/block, wave w: rows blk*64 + w*16. No LDS.
// A16: A-rows are fp16[128]; else f32[128] with convert.
template <int NC, bool A16>
__global__ __launch_bounds__(256) void mfma_gemm_k(const void* __restrict__ Xv,
                                                   const _Float16* __restrict__ Wp,
                                                   const float* __restrict__ dinv,
                                                   _Float16* __restrict__ H, int M) {
  constexpr int NF = NC / 16;
  int lane = threadIdx.x & 63;
  int w = threadIdx.x >> 6;
  int row0 = blockIdx.x * 64 + w * 16;
  int arow = row0 + (lane & 15);
  bool av = arow < M;
  const uint4* wp = (const uint4*)Wp;

  f32x4 acc[NF];
#pragma unroll
  for (int c = 0; c < NF; ++c) acc[c] = (f32x4){0.f, 0.f, 0.f, 0.f};

#pragma unroll
  for (int t = 0; t < 4; ++t) {
    f16x8 a;
    if constexpr (A16) {
      const _Float16* xr = (const _Float16*)Xv + (size_t)arow * 128 + ((lane >> 4) << 3);
      uint4 araw = av ? *(const uint4*)(xr + t * 32)
                      : make_uint4(0u, 0u, 0u, 0u);
      __builtin_memcpy(&a, &araw, 16);
    } else {
      const float* xr = (const float*)Xv + (size_t)arow * 128 + ((lane >> 4) << 3);
      float4 lo = av ? *(const float4*)(xr + t * 32)
                     : make_float4(0.f, 0.f, 0.f, 0.f);
      float4 hi = av ? *(const float4*)(xr + t * 32 + 4)
                     : make_float4(0.f, 0.f, 0.f, 0.f);
      a[0] = (_Float16)lo.x; a[1] = (_Float16)lo.y;
      a[2] = (_Float16)lo.z; a[3] = (_Float16)lo.w;
      a[4] = (_Float16)hi.x; a[5] = (_Float16)hi.y;
      a[6] = (_Float16)hi.z; a[7] = (_Float16)hi.w;
    }
#pragma unroll
    for (int c = 0; c < NF; ++c) {
      uint4 braw = wp[(t * NF + c) * 64 + lane];
      f16x8 b;
      __builtin_memcpy(&b, &braw, 16);
      acc[c] = __builtin_amdgcn_mfma_f32_16x16x32_f16(a, b, acc[c], 0, 0, 0);
    }
  }

  int rbase = row0 + ((lane >> 4) << 2);
#pragma unroll
  for (int r = 0; r < 4; ++r) {
    int row = rbase + r;
    if (row < M) {
      float di = dinv[row];
#pragma unroll
      for (int c = 0; c < NF; ++c)
        H[(size_t)row * NC + c * 16 + (lane & 15)] = (_Float16)(di * acc[c][r]);
    }
  }
}

// ---- agg1: y[i](fp16) = relu( dinv_i * (h'_i + sum_src h'_src) + b1 ), 128 feats ----
// h' rows: 64 uints (fp16x2) = 256B. Lane l holds feats 2l, 2l+1.
__global__ __launch_bounds__(256) void agg1_k(const uint* __restrict__ hp,
                                              const float* __restrict__ dinv,
                                              const int* __restrict__ offsets,
                                              const int* __restrict__ csr_src,
                                              const float* __restrict__ b,
                                              uint* __restrict__ y, int n) {
  int wave = threadIdx.x >> 6;
  int lane = threadIdx.x & 63;
  int node = blockIdx.x * NODES_PER_BLOCK + wave;
  if (node >= n) return;
  int beg = offsets[node], end = offsets[node + 1];
  int deg = end - beg;
  float2 self = h2f(hp[(size_t)node * 64 + lane]);
  float ax = self.x, ay = self.y;
  int sv = 0;
  if (lane < deg) sv = csr_src[beg + lane];
  int lim = deg < 64 ? deg : 64;
  int e = 0;
  for (; e + 8 <= lim; e += 8) {
    int s0 = __shfl(sv, e + 0), s1 = __shfl(sv, e + 1);
    int s2 = __shfl(sv, e + 2), s3 = __shfl(sv, e + 3);
    int s4 = __shfl(sv, e + 4), s5 = __shfl(sv, e + 5);
    int s6 = __shfl(sv, e + 6), s7 = __shfl(sv, e + 7);
    uint u0 = hp[(size_t)s0 * 64 + lane];
    uint u1 = hp[(size_t)s1 * 64 + lane];
    uint u2 = hp[(size_t)s2 * 64 + lane];
    uint u3 = hp[(size_t)s3 * 64 + lane];
    uint u4 = hp[(size_t)s4 * 64 + lane];
    uint u5 = hp[(size_t)s5 * 64 + lane];
    uint u6 = hp[(size_t)s6 * 64 + lane];
    uint u7 = hp[(size_t)s7 * 64 + lane];
    float2 v0 = h2f(u0), v1 = h2f(u1), v2 = h2f(u2), v3 = h2f(u3);
    float2 v4 = h2f(u4), v5 = h2f(u5), v6 = h2f(u6), v7 = h2f(u7);
    ax += ((v0.x + v1.x) + (v2.x + v3.x)) + ((v4.x + v5.x) + (v6.x + v7.x));
    ay += ((v0.y + v1.y) + (v2.y + v3.y)) + ((v4.y + v5.y) + (v6.y + v7.y));
  }
  for (; e < lim; ++e) {
    int s = __shfl(sv, e);
    float2 v = h2f(hp[(size_t)s * 64 + lane]);
    ax += v.x;
    ay += v.y;
  }
  for (int ee = beg + 64; ee < end; ++ee) {  // deg>64 fallback
    float2 v = h2f(hp[(size_t)csr_src[ee] * 64 + lane]);
    ax += v.x;
    ay += v.y;
  }
  float di = dinv[node];
  float2 bb = ((const float2*)b)[lane];
  float ox = fmaxf(fmaf(di, ax, bb.x), 0.0f);
  float oy = fmaxf(fmaf(di, ay, bb.y), 0.0f);
  y[(size_t)node * 64 + lane] = f2h(ox, oy);
}

// ---- agg2: out[i](f32) = dinv_i * (h'_i + sum_src h'_src) + b2, 64 feats ----
// h' rows: 32 uints (fp16x2) = 128B. One 32-lane SEGMENT per node: trip
// counts are segment-uniform, shuffles are width-32 (never cross segments).
__global__ __launch_bounds__(256) void agg2_k(const uint* __restrict__ hp,
                                              const float* __restrict__ dinv,
                                              const int* __restrict__ offsets,
                                              const int* __restrict__ csr_src,
                                              const float* __restrict__ b,
                                              float* __restrict__ out, int n) {
  int wv = threadIdx.x >> 6;     // wave in block 0..3
  int lane = threadIdx.x & 63;
  int half = lane >> 5;
  int fl = lane & 31;
  int node = blockIdx.x * 8 + wv * 2 + half;
  if (node >= n) return;  // uniform within segment
  int beg = offsets[node], end = offsets[node + 1];
  int deg = end - beg;
  float2 self = h2f(hp[(size_t)node * 32 + fl]);
  float ax = self.x, ay = self.y;
  int sv = 0;
  if (fl < deg) sv = csr_src[beg + fl];
  int lim = deg < 32 ? deg : 32;
  int e = 0;
  for (; e + 8 <= lim; e += 8) {
    int s0 = __shfl(sv, e + 0, 32), s1 = __shfl(sv, e + 1, 32);
    int s2 = __shfl(sv, e + 2, 32), s3 = __shfl(sv, e + 3, 32);
    int s4 = __shfl(sv, e + 4, 32), s5 = __shfl(sv, e + 5, 32);
    int s6 = __shfl(sv, e + 6, 32), s7 = __shfl(sv, e + 7, 32);
    uint u0 = hp[(size_t)s0 * 32 + fl];
    uint u1 = hp[(size_t)s1 * 32 + fl];
    uint u2 = hp[(size_t)s2 * 32 + fl];
    uint u3 = hp[(size_t)s3 * 32 + fl];
    uint u4 = hp[(size_t)s4 * 32 + fl];
    uint u5 = hp[(size_t)s5 * 32 + fl];
    uint u6 = hp[(size_t)s6 * 32 + fl];
    uint u7 = hp[(size_t)s7 * 32 + fl];
    float2 v0 = h2f(u0), v1 = h2f(u1), v2 = h2f(u2), v3 = h2f(u3);
    float2 v4 = h2f(u4), v5 = h2f(u5), v6 = h2f(u6), v7 = h2f(u7);
    ax += ((v0.x + v1.x) + (v2.x + v3.x)) + ((v4.x + v5.x) + (v6.x + v7.x));
    ay += ((v0.y + v1.y) + (v2.y + v3.y)) + ((v4.y + v5.y) + (v6.y + v7.y));
  }
  for (; e < lim; ++e) {
    int s = __shfl(sv, e, 32);
    float2 v = h2f(hp[(size_t)s * 32 + fl]);
    ax += v.x;
    ay += v.y;
  }
  for (int ee = beg + 32; ee < end; ++ee) {  // deg>32 fallback (uniform loads)
    float2 v = h2f(hp[(size_t)csr_src[ee] * 32 + fl]);
    ax += v.x;
    ay += v.y;
  }
  float di = dinv[node];
  float2 bb = ((const float2*)b)[fl];
  float2 o;
  o.x = fmaf(di, ax, bb.x);
  o.y = fmaf(di, ay, bb.y);
  ((float2*)out)[(size_t)node * 32 + fl] = o;
}

extern "C" void kernel_launch(void* const* d_in, const int* in_sizes, int n_in,
                              void* d_out, int out_size, void* d_ws, size_t ws_size,
                              hipStream_t stream) {
  const float* x  = (const float*)d_in[0];
  const int*   ei = (const int*)d_in[1];
  const float* W1 = (const float*)d_in[2];
  const float* b1 = (const float*)d_in[3];
  const float* W2 = (const float*)d_in[4];
  const float* b2 = (const float*)d_in[5];
  float* out = (float*)d_out;

  const int N = in_sizes[0] / 128;   // 50000
  const int E = in_sizes[1] / 2;     // 800000
  const int NBUCK = (N + 255) >> 8;             // 196
  const int NCHUNK = (E + CHUNK - 1) / CHUNK;   // 196

  char* w = (char*)d_ws;
  size_t off = 0;
  auto alloc = [&](size_t bytes) -> void* {
    void* p = w + off;
    off = (off + bytes + 511) & ~(size_t)511;
    return p;
  };
  int*       gh      = (int*)alloc((size_t)NBUCK * NCHUNK * 4);
  int*       totals  = (int*)alloc((size_t)NBUCK * 4);
  int*       bstart  = (int*)alloc((size_t)(NBUCK + 1) * 4);
  int*       flag    = (int*)alloc(64);
  int*       tmp     = (int*)alloc((size_t)E * 4);
  int*       offsets = (int*)alloc((size_t)(N + 1) * 4);
  float*     dinv    = (float*)alloc((size_t)N * 4);
  int*       csr_src = (int*)alloc((size_t)E * 4);
  _Float16*  pW1     = (_Float16*)alloc(16384 * 2);
  _Float16*  pW2     = (_Float16*)alloc(8192 * 2);
  _Float16*  h1      = (_Float16*)alloc((size_t)N * 128 * 2);  // fp16 [N][128]
  _Float16*  y       = (_Float16*)alloc((size_t)N * 128 * 2);  // fp16 [N][128]
  _Float16*  h2      = (_Float16*)alloc((size_t)N * 64 * 2);   // fp16 [N][64]

  const int GB  = (N + 63) / 64;
  const int AB  = (N + NODES_PER_BLOCK - 1) / NODES_PER_BLOCK;
  const int AB2 = (N + 7) / 8;

  detect64_k<<<1, 64, 0, stream>>>(ei, flag);
  hist_k<<<NCHUNK, 256, 0, stream>>>(ei, flag, gh, E, NCHUNK, NBUCK);
  tot_k<<<NBUCK, 256, 0, stream>>>(gh, totals, NCHUNK);
  scanrow_k<<<NBUCK, 256, 0, stream>>>(gh, totals, bstart, offsets, NCHUNK, NBUCK, N, E);
  part_k<<<NCHUNK, 256, 0, stream>>>(ei, flag, gh, tmp, E, NCHUNK, NBUCK);
  bucket_k<<<NBUCK, 256, 0, stream>>>(tmp, bstart, csr_src, offsets, dinv, N);

  prep_k<<<64, 256, 0, stream>>>(W1, pW1, 128, 16384);
  prep_k<<<32, 256, 0, stream>>>(W2, pW2, 64, 8192);

  mfma_gemm_k<128, false><<<GB, 256, 0, stream>>>(x, pW1, dinv, h1, N);
  agg1_k<<<AB, 256, 0, stream>>>((const uint*)h1, dinv, offsets, csr_src, b1,
                                 (uint*)y, N);
  mfma_gemm_k<64, true><<<GB, 256, 0, stream>>>(y, pW2, dinv, h2, N);
  agg2_k<<<AB2, 256, 0, stream>>>((const uint*)h2, dinv, offsets, csr_src, b2, out, N);
}